// Round 5
// baseline (263.971 us; speedup 1.0000x reference)
//
#include <hip/hip_runtime.h>
#include <hip/hip_cooperative_groups.h>
#include <float.h>
#include <math.h>

namespace cg = cooperative_groups;

#define BB 8
#define HH 256
#define WW 256
#define NPIX 65536          // HH*WW
#define TOT (BB*NPIX)
#define KTOP 80
#define NTIL 64             // 8x8 tiles of 32x32 per image
#define TCAP 128            // max candidates kept per tile
#define SELBINS 4096
#define SELCAP 2048
#define NBLK (BB*NTIL)      // 512
typedef unsigned long long ull;

// Phases time-share one LDS buffer (separate __shared__ arrays would SUM).
union SharedU {
    struct { float val[40][40]; float rs_o[40][32]; float rs_m[40][32]; } box;   // 35840 B
    struct { float sc[36][36]; float hm[36][32]; float bv[TCAP]; int bi[TCAP]; } nms; // 10816 B
    struct { unsigned hist[SELBINS]; ull keyAll[SELCAP]; unsigned bcs[NTIL]; unsigned scan[256]; } tk; // 34048 B
    struct { float4 lp[KTOP]; } sp;                                               // 1280 B
};

// ==================== cooperative mega-kernel ====================
__global__ void __launch_bounds__(256, 2)
k_mega(const float* __restrict__ vsm, const float* __restrict__ depth,
       float* __restrict__ out, char* __restrict__ ws)
{
    // workspace layout (pk first for 16B alignment)
    float4* pk   = (float4*)ws;                    // BB*KTOP
    float* prod  = (float*)(pk + BB*KTOP);         // TOT
    float* gauss = prod + TOT;                     // TOT
    float* pmn   = gauss + TOT;                    // NBLK
    float* pmx   = pmn + NBLK;
    float* gmn   = pmx + NBLK;
    float* gmx   = gmn + NBLK;
    unsigned* bcnt = (unsigned*)(gmx + NBLK);      // NBLK
    float* candV = (float*)(bcnt + NBLK);          // NBLK*TCAP
    int*   candI = (int*)(candV + NBLK*TCAP);      // NBLK*TCAP

    cg::grid_group grid = cg::this_grid();

    __shared__ SharedU sh;
    __shared__ float r0[256], r1[256];
    __shared__ float sred[2];
    __shared__ unsigned scnt;
    __shared__ int sBin;
    __shared__ unsigned sN;

    const int blk = blockIdx.x;
    const int tid = threadIdx.x;
    const int b   = blk >> 6;
    const int t   = blk & 63;
    const int ty0 = (t >> 3) << 5;
    const int tx0 = (t & 7) << 5;

    // ===== phase 1: fused 9x9 avg-pools -> prod + per-block min/max =====
    {
        for (int i = tid; i < 1600; i += 256) {
            int ly = i / 40, lx = i - ly * 40;
            int gy = ty0 - 4 + ly, gx = tx0 - 4 + lx;
            float v = 0.f;
            if (gy >= 0 && gy < HH && gx >= 0 && gx < WW)
                v = vsm[(b * HH + gy) * WW + gx];
            sh.box.val[ly][lx] = v;
        }
        __syncthreads();
        for (int i = tid; i < 1280; i += 256) {
            int ly = i >> 5, lx = i & 31;
            float so = 0.f, sm = 0.f;
            #pragma unroll
            for (int d = 0; d < 9; ++d) {
                float v = sh.box.val[ly][lx + d];
                so += (v > 0.2f) ? 1.f : 0.f;
                sm += v;
            }
            sh.box.rs_o[ly][lx] = so;
            sh.box.rs_m[ly][lx] = sm;
        }
        __syncthreads();
        int ox = tid & 31, oy0 = (tid >> 5) << 2;
        float tmn = FLT_MAX, tmx = -FLT_MAX;
        #pragma unroll
        for (int j = 0; j < 4; ++j) {
            int oy = oy0 + j;
            float so = 0.f, sm = 0.f;
            #pragma unroll
            for (int d = 0; d < 9; ++d) {
                so += sh.box.rs_o[oy + d][ox];
                sm += sh.box.rs_m[oy + d][ox];
            }
            float p = (so * (1.f / 81.f)) * (sm * (1.f / 81.f));
            prod[(b * HH + ty0 + oy) * WW + tx0 + ox] = p;
            tmn = fminf(tmn, p);
            tmx = fmaxf(tmx, p);
        }
        r0[tid] = tmn; r1[tid] = tmx;
        __syncthreads();
        for (int off = 128; off > 0; off >>= 1) {
            if (tid < off) {
                r0[tid] = fminf(r0[tid], r0[tid + off]);
                r1[tid] = fmaxf(r1[tid], r1[tid + off]);
            }
            __syncthreads();
        }
        if (tid == 0) { pmn[blk] = r0[0]; pmx[blk] = r1[0]; }
    }
    grid.sync();

    // ===== phase 2: score + 5x5 NMS + per-tile candidate compaction =====
    {
        if (tid < 64) {
            float mn = pmn[b * NTIL + tid];
            float mx = pmx[b * NTIL + tid];
            #pragma unroll
            for (int o = 32; o > 0; o >>= 1) {
                mn = fminf(mn, __shfl_xor(mn, o, 64));
                mx = fmaxf(mx, __shfl_xor(mx, o, 64));
            }
            if (tid == 0) { sred[0] = mn; sred[1] = mx; }
        }
        if (tid == 0) scnt = 0;
        __syncthreads();
        float mnp = sred[0];
        float inv = 1.f / (sred[1] - mnp + 1e-6f);

        for (int i = tid; i < 1296; i += 256) {
            int ly = i / 36, lx = i - ly * 36;
            int gy = ty0 - 2 + ly, gx = tx0 - 2 + lx;
            float s = -FLT_MAX;
            if (gy >= 0 && gy < HH && gx >= 0 && gx < WW) {
                int idx = (b * HH + gy) * WW + gx;
                s = vsm[idx] * ((prod[idx] - mnp) * inv);
            }
            sh.nms.sc[ly][lx] = s;
        }
        __syncthreads();
        for (int i = tid; i < 1152; i += 256) {
            int ly = i >> 5, lx = i & 31;
            float m = sh.nms.sc[ly][lx];
            #pragma unroll
            for (int d = 1; d < 5; ++d) m = fmaxf(m, sh.nms.sc[ly][lx + d]);
            sh.nms.hm[ly][lx] = m;
        }
        __syncthreads();
        int ox = tid & 31, oy0 = (tid >> 5) << 2;
        #pragma unroll
        for (int j = 0; j < 4; ++j) {
            int oy = oy0 + j;
            float m = sh.nms.hm[oy][ox];
            #pragma unroll
            for (int d = 1; d < 5; ++d) m = fmaxf(m, sh.nms.hm[oy + d][ox]);
            float s = sh.nms.sc[oy + 2][ox + 2];
            if (s == m && s > 0.f) {
                unsigned p = atomicAdd(&scnt, 1u);
                if (p < TCAP) {
                    sh.nms.bv[p] = s;
                    sh.nms.bi[p] = (ty0 + oy) * WW + tx0 + ox;
                }
            }
        }
        __syncthreads();
        unsigned cnt = min(scnt, (unsigned)TCAP);
        if (tid == 0) bcnt[blk] = cnt;
        for (unsigned i = tid; i < cnt; i += 256) {
            candV[blk * TCAP + i] = sh.nms.bv[i];
            candI[blk * TCAP + i] = sh.nms.bi[i];
        }
    }
    grid.sync();

    // ===== phase 3: per-batch exact top-80 (blocks 0..7) =====
    if (blk < BB) {
        const float* cv = candV + blk * NTIL * TCAP;
        const int*   ci = candI + blk * NTIL * TCAP;
        for (int i = tid; i < SELBINS; i += 256) sh.tk.hist[i] = 0;
        if (tid < NTIL) sh.tk.bcs[tid] = bcnt[blk * NTIL + tid];
        if (tid == 0) { sBin = 0; sN = 0; }
        __syncthreads();

        // histogram of float-bit bins (positive floats: bit order == value order)
        for (int i = tid; i < NTIL * TCAP; i += 256) {
            int tile = i >> 7, o = i & (TCAP - 1);
            if ((unsigned)o < sh.tk.bcs[tile])
                atomicAdd(&sh.tk.hist[__float_as_uint(cv[i]) >> 19], 1u);
        }
        __syncthreads();

        // suffix scan (16 bins/thread) -> boundary bin B
        int j0 = tid * 16;
        unsigned part = 0;
        #pragma unroll
        for (int j = 0; j < 16; ++j) part += sh.tk.hist[j0 + j];
        sh.tk.scan[tid] = part;
        __syncthreads();
        for (int off = 1; off < 256; off <<= 1) {
            unsigned v = (tid + off < 256) ? sh.tk.scan[tid + off] : 0u;
            __syncthreads();
            sh.tk.scan[tid] += v;
            __syncthreads();
        }
        unsigned run = sh.tk.scan[tid] - part;     // suffix sum of threads above
        for (int j = 15; j >= 0; --j) {
            unsigned h = sh.tk.hist[j0 + j];
            run += h;                              // run == suffix(j0+j)
            if (run >= KTOP && run - h < KTOP) sBin = j0 + j;
        }
        __syncthreads();

        // collect keys in bins >= B (key = valbits:~idx -> desc val, asc idx)
        int B = sBin;
        for (int i = tid; i < NTIL * TCAP; i += 256) {
            int tile = i >> 7, o = i & (TCAP - 1);
            if ((unsigned)o < sh.tk.bcs[tile]) {
                unsigned bits = __float_as_uint(cv[i]);
                if ((int)(bits >> 19) >= B) {
                    unsigned p = atomicAdd(&sN, 1u);
                    if (p < SELCAP)
                        sh.tk.keyAll[p] = ((ull)bits << 32) | (ull)(0xFFFFFFFFu - (unsigned)ci[i]);
                }
            }
        }
        __syncthreads();
        unsigned n = min(sN, (unsigned)SELCAP);
        unsigned P = 128; while (P < n) P <<= 1;
        for (unsigned i = n + tid; i < P; i += 256) sh.tk.keyAll[i] = 0ull;
        __syncthreads();

        // bitonic sort ascending; winners are the top (last) K entries
        for (unsigned k = 2; k <= P; k <<= 1) {
            for (unsigned j = k >> 1; j > 0; j >>= 1) {
                for (unsigned i = tid; i < P; i += 256) {
                    unsigned ixj = i ^ j;
                    if (ixj > i) {
                        ull a = sh.tk.keyAll[i], c = sh.tk.keyAll[ixj];
                        bool up = ((i & k) == 0);
                        if (up ? (a > c) : (a < c)) { sh.tk.keyAll[i] = c; sh.tk.keyAll[ixj] = a; }
                    }
                }
                __syncthreads();
            }
        }

        // emit packed peak params: {log2(val), x, y, c}
        if (tid < KTOP) {
            unsigned K = min((unsigned)KTOP, n);
            float plog = -INFINITY, fx = 0.f, fy = 0.f, c = 0.f;
            if ((unsigned)tid < K) {
                ull key = sh.tk.keyAll[P - 1 - tid];
                unsigned bits = (unsigned)(key >> 32);
                int idx = (int)(0xFFFFFFFFu - (unsigned)(key & 0xFFFFFFFFu));
                float val = __uint_as_float(bits);
                plog = log2f(val);
                fx = (float)(idx & 255);
                fy = (float)(idx >> 8);
                float z = fmaxf(depth[blk * NPIX + idx], 0.001f);
                float r = fminf(fmaxf(14.f / z, 1.5f), 18.f);
                float s2 = 0.36f * r * r;                     // (0.6*r)^2
                c = 1.44269504f / (2.f * s2 + 1e-6f);         // log2(e)/denom
            }
            pk[blk * KTOP + tid] = make_float4(plog, fx, fy, c);
        }
    }
    grid.sync();

    // ===== phase 4: log-domain gaussian splat (4 px/thread, 1 exp2/px) =====
    {
        int y0 = (blk & 63) << 2;
        if (tid < KTOP) sh.sp.lp[tid] = pk[b * KTOP + tid];
        __syncthreads();
        float fx = (float)tid;
        float fy = (float)y0;
        float g0 = -INFINITY, g1 = -INFINITY, g2 = -INFINITY, g3 = -INFINITY;
        #pragma unroll 4
        for (int k = 0; k < KTOP; ++k) {
            float4 q = sh.sp.lp[k];          // {plog, px, py, c}
            float dx = fx - q.y;
            float dx2 = dx * dx;
            float dy = fy - q.z;
            float d2;
            d2 = fmaf(dy, dy, dx2);          g0 = fmaxf(g0, fmaf(-d2, q.w, q.x));
            float dyb = dy + 1.f;
            d2 = fmaf(dyb, dyb, dx2);        g1 = fmaxf(g1, fmaf(-d2, q.w, q.x));
            float dyc = dy + 2.f;
            d2 = fmaf(dyc, dyc, dx2);        g2 = fmaxf(g2, fmaf(-d2, q.w, q.x));
            float dyd = dy + 3.f;
            d2 = fmaf(dyd, dyd, dx2);        g3 = fmaxf(g3, fmaf(-d2, q.w, q.x));
        }
        float v0 = exp2f(g0), v1 = exp2f(g1), v2 = exp2f(g2), v3 = exp2f(g3);
        int base = (b * HH + y0) * WW + tid;
        gauss[base]          = v0;
        gauss[base + WW]     = v1;
        gauss[base + 2 * WW] = v2;
        gauss[base + 3 * WW] = v3;

        float tmn = fminf(fminf(v0, v1), fminf(v2, v3));
        float tmx = fmaxf(fmaxf(v0, v1), fmaxf(v2, v3));
        r0[tid] = tmn; r1[tid] = tmx;
        __syncthreads();
        for (int off = 128; off > 0; off >>= 1) {
            if (tid < off) {
                r0[tid] = fminf(r0[tid], r0[tid + off]);
                r1[tid] = fmaxf(r1[tid], r1[tid + off]);
            }
            __syncthreads();
        }
        if (tid == 0) { gmn[blk] = r0[0]; gmx[blk] = r1[0]; }
    }
    grid.sync();

    // ===== phase 5: final norm01 (float4) =====
    {
        if (tid < 64) {
            float mn = gmn[b * NTIL + tid];
            float mx = gmx[b * NTIL + tid];
            #pragma unroll
            for (int o = 32; o > 0; o >>= 1) {
                mn = fminf(mn, __shfl_xor(mn, o, 64));
                mx = fmaxf(mx, __shfl_xor(mx, o, 64));
            }
            if (tid == 0) { sred[0] = mn; sred[1] = mx; }
        }
        __syncthreads();
        float mn = sred[0];
        float inv = 1.f / (sred[1] - mn + 1e-6f);
        int i = blk * 256 + tid;                 // float4 index
        float4 v = ((const float4*)gauss)[i];
        v.x = (v.x - mn) * inv;
        v.y = (v.y - mn) * inv;
        v.z = (v.z - mn) * inv;
        v.w = (v.w - mn) * inv;
        ((float4*)out)[i] = v;
    }
}

// ==================== fallback path: round-4 five-kernel pipeline ====================
__global__ void k_box9(const float* __restrict__ vsm, float* __restrict__ prod,
                       float* __restrict__ pmn, float* __restrict__ pmx) {
    int blk = blockIdx.x;
    int b = blk >> 6, t = blk & 63;
    int ty0 = (t >> 3) << 5, tx0 = (t & 7) << 5;
    int tid = threadIdx.x;
    __shared__ float val[40][40];
    __shared__ float rs_o[40][32];
    __shared__ float rs_m[40][32];
    for (int i = tid; i < 1600; i += 256) {
        int ly = i / 40, lx = i - ly * 40;
        int gy = ty0 - 4 + ly, gx = tx0 - 4 + lx;
        float v = 0.f;
        if (gy >= 0 && gy < HH && gx >= 0 && gx < WW) v = vsm[(b * HH + gy) * WW + gx];
        val[ly][lx] = v;
    }
    __syncthreads();
    for (int i = tid; i < 1280; i += 256) {
        int ly = i >> 5, lx = i & 31;
        float so = 0.f, sm = 0.f;
        #pragma unroll
        for (int d = 0; d < 9; ++d) { float v = val[ly][lx + d]; so += (v > 0.2f) ? 1.f : 0.f; sm += v; }
        rs_o[ly][lx] = so; rs_m[ly][lx] = sm;
    }
    __syncthreads();
    int ox = tid & 31, oy0 = (tid >> 5) << 2;
    float tmn = FLT_MAX, tmx = -FLT_MAX;
    #pragma unroll
    for (int j = 0; j < 4; ++j) {
        int oy = oy0 + j;
        float so = 0.f, sm = 0.f;
        #pragma unroll
        for (int d = 0; d < 9; ++d) { so += rs_o[oy + d][ox]; sm += rs_m[oy + d][ox]; }
        float p = (so * (1.f / 81.f)) * (sm * (1.f / 81.f));
        prod[(b * HH + ty0 + oy) * WW + tx0 + ox] = p;
        tmn = fminf(tmn, p); tmx = fmaxf(tmx, p);
    }
    __shared__ float smn[256], smx[256];
    smn[tid] = tmn; smx[tid] = tmx;
    __syncthreads();
    for (int off = 128; off > 0; off >>= 1) {
        if (tid < off) { smn[tid] = fminf(smn[tid], smn[tid + off]); smx[tid] = fmaxf(smx[tid], smx[tid + off]); }
        __syncthreads();
    }
    if (tid == 0) { pmn[blk] = smn[0]; pmx[blk] = smx[0]; }
}

__global__ void k_nms(const float* __restrict__ vsm, const float* __restrict__ prod,
                      const float* __restrict__ pmn, const float* __restrict__ pmx,
                      unsigned* __restrict__ bcnt, float* __restrict__ candV,
                      int* __restrict__ candI) {
    int blk = blockIdx.x;
    int b = blk >> 6, t = blk & 63;
    int ty0 = (t >> 3) << 5, tx0 = (t & 7) << 5;
    int tid = threadIdx.x;
    __shared__ float sred[2];
    if (tid < 64) {
        float mn = pmn[b * NTIL + tid];
        float mx = pmx[b * NTIL + tid];
        #pragma unroll
        for (int o = 32; o > 0; o >>= 1) { mn = fminf(mn, __shfl_xor(mn, o, 64)); mx = fmaxf(mx, __shfl_xor(mx, o, 64)); }
        if (tid == 0) { sred[0] = mn; sred[1] = mx; }
    }
    __syncthreads();
    float mnp = sred[0];
    float inv = 1.f / (sred[1] - mnp + 1e-6f);
    __shared__ float sc[36][36];
    __shared__ float hm[36][32];
    for (int i = tid; i < 1296; i += 256) {
        int ly = i / 36, lx = i - ly * 36;
        int gy = ty0 - 2 + ly, gx = tx0 - 2 + lx;
        float s = -FLT_MAX;
        if (gy >= 0 && gy < HH && gx >= 0 && gx < WW) {
            int idx = (b * HH + gy) * WW + gx;
            s = vsm[idx] * ((prod[idx] - mnp) * inv);
        }
        sc[ly][lx] = s;
    }
    __syncthreads();
    for (int i = tid; i < 1152; i += 256) {
        int ly = i >> 5, lx = i & 31;
        float m = sc[ly][lx];
        #pragma unroll
        for (int d = 1; d < 5; ++d) m = fmaxf(m, sc[ly][lx + d]);
        hm[ly][lx] = m;
    }
    __syncthreads();
    __shared__ unsigned scnt;
    __shared__ float bv[TCAP];
    __shared__ int bi[TCAP];
    if (tid == 0) scnt = 0;
    __syncthreads();
    int ox = tid & 31, oy0 = (tid >> 5) << 2;
    #pragma unroll
    for (int j = 0; j < 4; ++j) {
        int oy = oy0 + j;
        float m = hm[oy][ox];
        #pragma unroll
        for (int d = 1; d < 5; ++d) m = fmaxf(m, hm[oy + d][ox]);
        float s = sc[oy + 2][ox + 2];
        if (s == m && s > 0.f) {
            unsigned p = atomicAdd(&scnt, 1u);
            if (p < TCAP) { bv[p] = s; bi[p] = (ty0 + oy) * WW + tx0 + ox; }
        }
    }
    __syncthreads();
    unsigned cnt = min(scnt, (unsigned)TCAP);
    if (tid == 0) bcnt[blk] = cnt;
    for (unsigned i = tid; i < cnt; i += 256) {
        candV[blk * TCAP + i] = bv[i];
        candI[blk * TCAP + i] = bi[i];
    }
}

__global__ void __launch_bounds__(1024)
k_topk(const float* __restrict__ depth, const unsigned* __restrict__ bcnt,
       const float* __restrict__ candV, const int* __restrict__ candI,
       float4* __restrict__ pk) {
    int b = blockIdx.x;
    int tid = threadIdx.x;
    __shared__ unsigned hist[SELBINS];
    __shared__ unsigned sc[1024];
    __shared__ ull keyAll[SELCAP];
    __shared__ unsigned bcs[NTIL];
    __shared__ int sBin;
    __shared__ unsigned sN;
    const float* cv = candV + b * NTIL * TCAP;
    const int* ci = candI + b * NTIL * TCAP;
    #pragma unroll
    for (int i = 0; i < SELBINS / 1024; ++i) hist[tid + i * 1024] = 0;
    if (tid < NTIL) bcs[tid] = bcnt[b * NTIL + tid];
    if (tid == 0) { sBin = 0; sN = 0; }
    __syncthreads();
    for (int i = tid; i < NTIL * TCAP; i += 1024) {
        int tile = i >> 7, o = i & (TCAP - 1);
        if ((unsigned)o < bcs[tile]) atomicAdd(&hist[__float_as_uint(cv[i]) >> 19], 1u);
    }
    __syncthreads();
    int j0 = tid * 4;
    unsigned h0 = hist[j0], h1 = hist[j0 + 1], h2 = hist[j0 + 2], h3 = hist[j0 + 3];
    unsigned part = h0 + h1 + h2 + h3;
    sc[tid] = part;
    __syncthreads();
    for (int off = 1; off < 1024; off <<= 1) {
        unsigned v = (tid + off < 1024) ? sc[tid + off] : 0u;
        __syncthreads();
        sc[tid] += v;
        __syncthreads();
    }
    unsigned excl = sc[tid] - part;
    unsigned suf3 = excl + h3, suf2 = suf3 + h2, suf1 = suf2 + h1, suf0 = suf1 + h0;
    if (suf0 >= KTOP && suf0 - h0 < KTOP) sBin = j0;
    if (suf1 >= KTOP && suf1 - h1 < KTOP) sBin = j0 + 1;
    if (suf2 >= KTOP && suf2 - h2 < KTOP) sBin = j0 + 2;
    if (suf3 >= KTOP && suf3 - h3 < KTOP) sBin = j0 + 3;
    __syncthreads();
    int B = sBin;
    for (int i = tid; i < NTIL * TCAP; i += 1024) {
        int tile = i >> 7, o = i & (TCAP - 1);
        if ((unsigned)o < bcs[tile]) {
            unsigned bits = __float_as_uint(cv[i]);
            if ((int)(bits >> 19) >= B) {
                unsigned p = atomicAdd(&sN, 1u);
                if (p < SELCAP) keyAll[p] = ((ull)bits << 32) | (ull)(0xFFFFFFFFu - (unsigned)ci[i]);
            }
        }
    }
    __syncthreads();
    unsigned n = min(sN, (unsigned)SELCAP);
    unsigned P = 128; while (P < n) P <<= 1;
    for (unsigned i = n + tid; i < P; i += 1024) keyAll[i] = 0ull;
    __syncthreads();
    for (unsigned k = 2; k <= P; k <<= 1) {
        for (unsigned j = k >> 1; j > 0; j >>= 1) {
            for (unsigned i = tid; i < P; i += 1024) {
                unsigned ixj = i ^ j;
                if (ixj > i) {
                    ull a = keyAll[i], c = keyAll[ixj];
                    bool up = ((i & k) == 0);
                    if (up ? (a > c) : (a < c)) { keyAll[i] = c; keyAll[ixj] = a; }
                }
            }
            __syncthreads();
        }
    }
    if (tid < KTOP) {
        unsigned K = min((unsigned)KTOP, n);
        float plog = -INFINITY, fx = 0.f, fy = 0.f, c = 0.f;
        if ((unsigned)tid < K) {
            ull key = keyAll[P - 1 - tid];
            unsigned bits = (unsigned)(key >> 32);
            int idx = (int)(0xFFFFFFFFu - (unsigned)(key & 0xFFFFFFFFu));
            float val = __uint_as_float(bits);
            plog = log2f(val);
            fx = (float)(idx & 255);
            fy = (float)(idx >> 8);
            float z = fmaxf(depth[b * NPIX + idx], 0.001f);
            float r = fminf(fmaxf(14.f / z, 1.5f), 18.f);
            float s2 = 0.36f * r * r;
            c = 1.44269504f / (2.f * s2 + 1e-6f);
        }
        pk[b * KTOP + tid] = make_float4(plog, fx, fy, c);
    }
}

__global__ void k_splat(const float4* __restrict__ pk, float* __restrict__ gauss,
                        float* __restrict__ gmn, float* __restrict__ gmx) {
    int blk = blockIdx.x;
    int b = blk >> 6;
    int y0 = (blk & 63) << 2;
    int x = threadIdx.x;
    __shared__ float4 lp[KTOP];
    if (x < KTOP) lp[x] = pk[b * KTOP + x];
    __syncthreads();
    float fx = (float)x, fy = (float)y0;
    float g0 = -INFINITY, g1 = -INFINITY, g2 = -INFINITY, g3 = -INFINITY;
    #pragma unroll 4
    for (int k = 0; k < KTOP; ++k) {
        float4 q = lp[k];
        float dx = fx - q.y;
        float dx2 = dx * dx;
        float dy = fy - q.z;
        float d2;
        d2 = fmaf(dy, dy, dx2);        g0 = fmaxf(g0, fmaf(-d2, q.w, q.x));
        float dyb = dy + 1.f;
        d2 = fmaf(dyb, dyb, dx2);      g1 = fmaxf(g1, fmaf(-d2, q.w, q.x));
        float dyc = dy + 2.f;
        d2 = fmaf(dyc, dyc, dx2);      g2 = fmaxf(g2, fmaf(-d2, q.w, q.x));
        float dyd = dy + 3.f;
        d2 = fmaf(dyd, dyd, dx2);      g3 = fmaxf(g3, fmaf(-d2, q.w, q.x));
    }
    float v0 = exp2f(g0), v1 = exp2f(g1), v2 = exp2f(g2), v3 = exp2f(g3);
    int base = (b * HH + y0) * WW + x;
    gauss[base] = v0; gauss[base + WW] = v1; gauss[base + 2 * WW] = v2; gauss[base + 3 * WW] = v3;
    float tmn = fminf(fminf(v0, v1), fminf(v2, v3));
    float tmx = fmaxf(fmaxf(v0, v1), fmaxf(v2, v3));
    __shared__ float smn[256], smx[256];
    smn[x] = tmn; smx[x] = tmx;
    __syncthreads();
    for (int off = 128; off > 0; off >>= 1) {
        if (x < off) { smn[x] = fminf(smn[x], smn[x + off]); smx[x] = fmaxf(smx[x], smx[x + off]); }
        __syncthreads();
    }
    if (x == 0) { gmn[blk] = smn[0]; gmx[blk] = smx[0]; }
}

__global__ void k_norm(const float* __restrict__ gauss, const float* __restrict__ gmn,
                       const float* __restrict__ gmx, float* __restrict__ out) {
    int blk = blockIdx.x;
    int b = blk >> 6;
    int tid = threadIdx.x;
    __shared__ float sred[2];
    if (tid < 64) {
        float mn = gmn[b * NTIL + tid];
        float mx = gmx[b * NTIL + tid];
        #pragma unroll
        for (int o = 32; o > 0; o >>= 1) { mn = fminf(mn, __shfl_xor(mn, o, 64)); mx = fmaxf(mx, __shfl_xor(mx, o, 64)); }
        if (tid == 0) { sred[0] = mn; sred[1] = mx; }
    }
    __syncthreads();
    float mn = sred[0];
    float inv = 1.f / (sred[1] - mn + 1e-6f);
    int i = blk * 256 + tid;
    float4 v = ((const float4*)gauss)[i];
    v.x = (v.x - mn) * inv;
    v.y = (v.y - mn) * inv;
    v.z = (v.z - mn) * inv;
    v.w = (v.w - mn) * inv;
    ((float4*)out)[i] = v;
}

extern "C" void kernel_launch(void* const* d_in, const int* in_sizes, int n_in,
                              void* d_out, int out_size, void* d_ws, size_t ws_size,
                              hipStream_t stream) {
    const float* vsm   = (const float*)d_in[0];
    const float* depth = (const float*)d_in[1];
    float* out = (float*)d_out;
    char* ws = (char*)d_ws;

    void* kargs[] = { (void*)&vsm, (void*)&depth, (void*)&out, (void*)&ws };
    hipError_t err = hipLaunchCooperativeKernel((const void*)k_mega, dim3(NBLK), dim3(256),
                                                kargs, 0, stream);
    if (err == hipSuccess) return;

    // fallback: proven 5-kernel pipeline (identical math / outputs)
    float4* pk = (float4*)d_ws;
    float* prod = (float*)(pk + BB * KTOP);
    float* gauss = prod + TOT;
    float* pmn = gauss + TOT;
    float* pmx = pmn + NBLK;
    float* gmn = pmx + NBLK;
    float* gmx = gmn + NBLK;
    unsigned* bcnt = (unsigned*)(gmx + NBLK);
    float* candV = (float*)(bcnt + NBLK);
    int* candI = (int*)(candV + NBLK * TCAP);

    k_box9 <<<NBLK, 256, 0, stream>>>(vsm, prod, pmn, pmx);
    k_nms  <<<NBLK, 256, 0, stream>>>(vsm, prod, pmn, pmx, bcnt, candV, candI);
    k_topk <<<BB, 1024, 0, stream>>>(depth, bcnt, candV, candI, pk);
    k_splat<<<NBLK, 256, 0, stream>>>(pk, gauss, gmn, gmx);
    k_norm <<<NBLK, 256, 0, stream>>>(gauss, gmn, gmx, out);
}

// Round 6
// 117.798 us; speedup vs baseline: 2.2409x; 2.2409x over previous
//
#include <hip/hip_runtime.h>
#include <float.h>
#include <math.h>

#define BB 8
#define HH 256
#define WW 256
#define NPIX 65536          // HH*WW
#define TOT (BB*NPIX)
#define KTOP 80
#define NTIL 64             // 8x8 tiles of 32x32 per image
#define TCAP 128            // max candidates kept per tile
#define SELBINS 4096
#define SELCAP 2048
#define NBLK (BB*NTIL)      // 512
#define BARSTRIDE 32        // uints (128 B) per barrier slot
#define NBAR 3
typedef unsigned long long ull;

// Phases time-share one LDS buffer (separate __shared__ arrays would SUM).
union SharedU {
    struct { float val[40][40]; float rs_o[40][32]; float rs_m[40][32]; } box;        // 35840 B
    struct { float sc[36][36]; float hm[36][32]; float bv[TCAP]; int bi[TCAP]; } nms;  // 10816 B
    struct { unsigned hist[SELBINS]; ull keyAll[SELCAP]; unsigned bcs[NTIL]; unsigned scan[256]; } tk; // 34048 B
};

// per-batch barrier: 64 blocks, monotone counter (memset to 0 each call)
__device__ __forceinline__ void batch_bar(unsigned* slot) {
    __syncthreads();
    if (threadIdx.x == 0) {
        __hip_atomic_fetch_add(slot, 1u, __ATOMIC_ACQ_REL, __HIP_MEMORY_SCOPE_AGENT);
        while (__hip_atomic_load(slot, __ATOMIC_ACQUIRE, __HIP_MEMORY_SCOPE_AGENT) < (unsigned)NTIL)
            __builtin_amdgcn_s_sleep(1);
    }
    __syncthreads();
}

// ==================== cooperative mega-kernel (hand-rolled per-batch sync) ====================
__global__ void __launch_bounds__(256, 2)
k_mega(const float* __restrict__ vsm, const float* __restrict__ depth,
       float* __restrict__ out, char* __restrict__ ws)
{
    unsigned* bar  = (unsigned*)ws;                     // 8*3 slots, 128B stride
    float4* pk     = (float4*)(ws + BB*NBAR*BARSTRIDE*4); // fallback-only slot (keeps layout shared)
    float* prod    = (float*)(pk + BB*KTOP);            // TOT
    float* gauss   = prod + TOT;                        // TOT
    float* pmn     = gauss + TOT;                       // NBLK
    float* pmx     = pmn + NBLK;
    float* gmn     = pmx + NBLK;
    float* gmx     = gmn + NBLK;
    unsigned* bcnt = (unsigned*)(gmx + NBLK);           // NBLK
    float* candV   = (float*)(bcnt + NBLK);             // NBLK*TCAP
    int*   candI   = (int*)(candV + NBLK*TCAP);         // NBLK*TCAP

    __shared__ SharedU sh;
    __shared__ float4 lp[KTOP];
    __shared__ float r0[256], r1[256];
    __shared__ float sred[2];
    __shared__ unsigned scnt;
    __shared__ int sBin;
    __shared__ unsigned sN;

    const int blk = blockIdx.x;
    const int tid = threadIdx.x;
    const int b   = blk >> 6;
    const int t   = blk & 63;
    const int ty0 = (t >> 3) << 5;
    const int tx0 = (t & 7) << 5;
    unsigned* mybar = bar + b * NBAR * BARSTRIDE;

    // ===== phase 1: fused 9x9 avg-pools -> prod + per-block min/max partials =====
    {
        for (int i = tid; i < 1600; i += 256) {
            int ly = i / 40, lx = i - ly * 40;
            int gy = ty0 - 4 + ly, gx = tx0 - 4 + lx;
            float v = 0.f;
            if (gy >= 0 && gy < HH && gx >= 0 && gx < WW)
                v = vsm[(b * HH + gy) * WW + gx];
            sh.box.val[ly][lx] = v;
        }
        __syncthreads();
        for (int i = tid; i < 1280; i += 256) {
            int ly = i >> 5, lx = i & 31;
            float so = 0.f, sm = 0.f;
            #pragma unroll
            for (int d = 0; d < 9; ++d) {
                float v = sh.box.val[ly][lx + d];
                so += (v > 0.2f) ? 1.f : 0.f;
                sm += v;
            }
            sh.box.rs_o[ly][lx] = so;
            sh.box.rs_m[ly][lx] = sm;
        }
        __syncthreads();
        int ox = tid & 31, oy0 = (tid >> 5) << 2;
        float tmn = FLT_MAX, tmx = -FLT_MAX;
        #pragma unroll
        for (int j = 0; j < 4; ++j) {
            int oy = oy0 + j;
            float so = 0.f, sm = 0.f;
            #pragma unroll
            for (int d = 0; d < 9; ++d) {
                so += sh.box.rs_o[oy + d][ox];
                sm += sh.box.rs_m[oy + d][ox];
            }
            float p = (so * (1.f / 81.f)) * (sm * (1.f / 81.f));
            prod[(b * HH + ty0 + oy) * WW + tx0 + ox] = p;
            tmn = fminf(tmn, p);
            tmx = fmaxf(tmx, p);
        }
        r0[tid] = tmn; r1[tid] = tmx;
        __syncthreads();
        for (int off = 128; off > 0; off >>= 1) {
            if (tid < off) {
                r0[tid] = fminf(r0[tid], r0[tid + off]);
                r1[tid] = fmaxf(r1[tid], r1[tid + off]);
            }
            __syncthreads();
        }
        if (tid == 0) { pmn[blk] = r0[0]; pmx[blk] = r1[0]; }
    }
    batch_bar(mybar + 0 * BARSTRIDE);

    // ===== phase 2: score + 5x5 NMS + per-tile candidate compaction =====
    {
        if (tid < 64) {
            float mn = pmn[b * NTIL + tid];
            float mx = pmx[b * NTIL + tid];
            #pragma unroll
            for (int o = 32; o > 0; o >>= 1) {
                mn = fminf(mn, __shfl_xor(mn, o, 64));
                mx = fmaxf(mx, __shfl_xor(mx, o, 64));
            }
            if (tid == 0) { sred[0] = mn; sred[1] = mx; }
        }
        if (tid == 0) scnt = 0;
        __syncthreads();
        float mnp = sred[0];
        float inv = 1.f / (sred[1] - mnp + 1e-6f);

        for (int i = tid; i < 1296; i += 256) {
            int ly = i / 36, lx = i - ly * 36;
            int gy = ty0 - 2 + ly, gx = tx0 - 2 + lx;
            float s = -FLT_MAX;
            if (gy >= 0 && gy < HH && gx >= 0 && gx < WW) {
                int idx = (b * HH + gy) * WW + gx;
                s = vsm[idx] * ((prod[idx] - mnp) * inv);
            }
            sh.nms.sc[ly][lx] = s;
        }
        __syncthreads();
        for (int i = tid; i < 1152; i += 256) {
            int ly = i >> 5, lx = i & 31;
            float m = sh.nms.sc[ly][lx];
            #pragma unroll
            for (int d = 1; d < 5; ++d) m = fmaxf(m, sh.nms.sc[ly][lx + d]);
            sh.nms.hm[ly][lx] = m;
        }
        __syncthreads();
        int ox = tid & 31, oy0 = (tid >> 5) << 2;
        #pragma unroll
        for (int j = 0; j < 4; ++j) {
            int oy = oy0 + j;
            float m = sh.nms.hm[oy][ox];
            #pragma unroll
            for (int d = 1; d < 5; ++d) m = fmaxf(m, sh.nms.hm[oy + d][ox]);
            float s = sh.nms.sc[oy + 2][ox + 2];
            if (s == m && s > 0.f) {
                unsigned p = atomicAdd(&scnt, 1u);
                if (p < TCAP) {
                    sh.nms.bv[p] = s;
                    sh.nms.bi[p] = (ty0 + oy) * WW + tx0 + ox;
                }
            }
        }
        __syncthreads();
        unsigned cnt = min(scnt, (unsigned)TCAP);
        if (tid == 0) bcnt[blk] = cnt;
        for (unsigned i = tid; i < cnt; i += 256) {
            candV[blk * TCAP + i] = sh.nms.bv[i];
            candI[blk * TCAP + i] = sh.nms.bi[i];
        }
    }
    batch_bar(mybar + 1 * BARSTRIDE);

    // ===== phase 3: redundant per-block top-80 of this batch -> lp[] in LDS =====
    {
        const float* cv = candV + b * NTIL * TCAP;
        const int*   ci = candI + b * NTIL * TCAP;
        for (int i = tid; i < SELBINS; i += 256) sh.tk.hist[i] = 0;
        if (tid < NTIL) sh.tk.bcs[tid] = bcnt[b * NTIL + tid];
        if (tid == 0) { sBin = 0; sN = 0; }
        __syncthreads();

        // histogram of float-bit bins (positive floats: bit order == value order)
        for (int i = tid; i < NTIL * TCAP; i += 256) {
            int tile = i >> 7, o = i & (TCAP - 1);
            if ((unsigned)o < sh.tk.bcs[tile])
                atomicAdd(&sh.tk.hist[__float_as_uint(cv[i]) >> 19], 1u);
        }
        __syncthreads();

        // suffix scan (16 bins/thread) -> boundary bin B with suffix(B) >= KTOP
        int j0 = tid * 16;
        unsigned part = 0;
        #pragma unroll
        for (int j = 0; j < 16; ++j) part += sh.tk.hist[j0 + j];
        sh.tk.scan[tid] = part;
        __syncthreads();
        for (int off = 1; off < 256; off <<= 1) {
            unsigned v = (tid + off < 256) ? sh.tk.scan[tid + off] : 0u;
            __syncthreads();
            sh.tk.scan[tid] += v;
            __syncthreads();
        }
        unsigned run = sh.tk.scan[tid] - part;     // suffix sum of threads above
        for (int j = 15; j >= 0; --j) {
            unsigned h = sh.tk.hist[j0 + j];
            run += h;                              // run == suffix(j0+j)
            if (run >= KTOP && run - h < KTOP) sBin = j0 + j;
        }
        __syncthreads();

        // collect keys in bins >= B (key = valbits:~idx -> desc val, asc idx)
        int B = sBin;
        for (int i = tid; i < NTIL * TCAP; i += 256) {
            int tile = i >> 7, o = i & (TCAP - 1);
            if ((unsigned)o < sh.tk.bcs[tile]) {
                unsigned bits = __float_as_uint(cv[i]);
                if ((int)(bits >> 19) >= B) {
                    unsigned p = atomicAdd(&sN, 1u);
                    if (p < SELCAP)
                        sh.tk.keyAll[p] = ((ull)bits << 32) | (ull)(0xFFFFFFFFu - (unsigned)ci[i]);
                }
            }
        }
        __syncthreads();
        unsigned n = min(sN, (unsigned)SELCAP);
        unsigned P = 128; while (P < n) P <<= 1;
        for (unsigned i = n + tid; i < P; i += 256) sh.tk.keyAll[i] = 0ull;
        __syncthreads();

        // bitonic sort ascending; winners are the top (last) K entries
        for (unsigned k = 2; k <= P; k <<= 1) {
            for (unsigned j = k >> 1; j > 0; j >>= 1) {
                for (unsigned i = tid; i < P; i += 256) {
                    unsigned ixj = i ^ j;
                    if (ixj > i) {
                        ull a = sh.tk.keyAll[i], c = sh.tk.keyAll[ixj];
                        bool up = ((i & k) == 0);
                        if (up ? (a > c) : (a < c)) { sh.tk.keyAll[i] = c; sh.tk.keyAll[ixj] = a; }
                    }
                }
                __syncthreads();
            }
        }

        // emit packed peak params into LDS: {log2(val), x, y, c}
        if (tid < KTOP) {
            unsigned K = min((unsigned)KTOP, n);
            float plog = -INFINITY, fx = 0.f, fy = 0.f, c = 0.f;
            if ((unsigned)tid < K) {
                ull key = sh.tk.keyAll[P - 1 - tid];
                unsigned bits = (unsigned)(key >> 32);
                int idx = (int)(0xFFFFFFFFu - (unsigned)(key & 0xFFFFFFFFu));
                float val = __uint_as_float(bits);
                plog = log2f(val);
                fx = (float)(idx & 255);
                fy = (float)(idx >> 8);
                float z = fmaxf(depth[b * NPIX + idx], 0.001f);
                float r = fminf(fmaxf(14.f / z, 1.5f), 18.f);
                float s2 = 0.36f * r * r;                     // (0.6*r)^2
                c = 1.44269504f / (2.f * s2 + 1e-6f);         // log2(e)/denom
            }
            lp[tid] = make_float4(plog, fx, fy, c);
        }
        __syncthreads();
    }
    // no barrier needed: each block computed its own lp

    // ===== phase 4: log-domain gaussian splat (4 px/thread, 1 exp2/px) =====
    {
        int y0 = t << 2;
        float fx = (float)tid;
        float fy = (float)y0;
        float g0 = -INFINITY, g1 = -INFINITY, g2 = -INFINITY, g3 = -INFINITY;
        #pragma unroll 4
        for (int k = 0; k < KTOP; ++k) {
            float4 q = lp[k];                // {plog, px, py, c}
            float dx = fx - q.y;
            float dx2 = dx * dx;
            float dy = fy - q.z;
            float d2;
            d2 = fmaf(dy, dy, dx2);          g0 = fmaxf(g0, fmaf(-d2, q.w, q.x));
            float dyb = dy + 1.f;
            d2 = fmaf(dyb, dyb, dx2);        g1 = fmaxf(g1, fmaf(-d2, q.w, q.x));
            float dyc = dy + 2.f;
            d2 = fmaf(dyc, dyc, dx2);        g2 = fmaxf(g2, fmaf(-d2, q.w, q.x));
            float dyd = dy + 3.f;
            d2 = fmaf(dyd, dyd, dx2);        g3 = fmaxf(g3, fmaf(-d2, q.w, q.x));
        }
        float v0 = exp2f(g0), v1 = exp2f(g1), v2 = exp2f(g2), v3 = exp2f(g3);
        int base = (b * HH + y0) * WW + tid;
        gauss[base]          = v0;
        gauss[base + WW]     = v1;
        gauss[base + 2 * WW] = v2;
        gauss[base + 3 * WW] = v3;

        float tmn = fminf(fminf(v0, v1), fminf(v2, v3));
        float tmx = fmaxf(fmaxf(v0, v1), fmaxf(v2, v3));
        r0[tid] = tmn; r1[tid] = tmx;
        __syncthreads();
        for (int off = 128; off > 0; off >>= 1) {
            if (tid < off) {
                r0[tid] = fminf(r0[tid], r0[tid + off]);
                r1[tid] = fmaxf(r1[tid], r1[tid + off]);
            }
            __syncthreads();
        }
        if (tid == 0) { gmn[blk] = r0[0]; gmx[blk] = r1[0]; }
    }
    batch_bar(mybar + 2 * BARSTRIDE);

    // ===== phase 5: final norm01 (float4) =====
    {
        if (tid < 64) {
            float mn = gmn[b * NTIL + tid];
            float mx = gmx[b * NTIL + tid];
            #pragma unroll
            for (int o = 32; o > 0; o >>= 1) {
                mn = fminf(mn, __shfl_xor(mn, o, 64));
                mx = fmaxf(mx, __shfl_xor(mx, o, 64));
            }
            if (tid == 0) { sred[0] = mn; sred[1] = mx; }
        }
        __syncthreads();
        float mn = sred[0];
        float inv = 1.f / (sred[1] - mn + 1e-6f);
        int i = blk * 256 + tid;                 // float4 index
        float4 v = ((const float4*)gauss)[i];
        v.x = (v.x - mn) * inv;
        v.y = (v.y - mn) * inv;
        v.z = (v.z - mn) * inv;
        v.w = (v.w - mn) * inv;
        ((float4*)out)[i] = v;
    }
}

// ==================== fallback path: round-4 five-kernel pipeline (proven 42 µs) ====================
__global__ void k_box9(const float* __restrict__ vsm, float* __restrict__ prod,
                       float* __restrict__ pmn, float* __restrict__ pmx) {
    int blk = blockIdx.x;
    int b = blk >> 6, t = blk & 63;
    int ty0 = (t >> 3) << 5, tx0 = (t & 7) << 5;
    int tid = threadIdx.x;
    __shared__ float val[40][40];
    __shared__ float rs_o[40][32];
    __shared__ float rs_m[40][32];
    for (int i = tid; i < 1600; i += 256) {
        int ly = i / 40, lx = i - ly * 40;
        int gy = ty0 - 4 + ly, gx = tx0 - 4 + lx;
        float v = 0.f;
        if (gy >= 0 && gy < HH && gx >= 0 && gx < WW) v = vsm[(b * HH + gy) * WW + gx];
        val[ly][lx] = v;
    }
    __syncthreads();
    for (int i = tid; i < 1280; i += 256) {
        int ly = i >> 5, lx = i & 31;
        float so = 0.f, sm = 0.f;
        #pragma unroll
        for (int d = 0; d < 9; ++d) { float v = val[ly][lx + d]; so += (v > 0.2f) ? 1.f : 0.f; sm += v; }
        rs_o[ly][lx] = so; rs_m[ly][lx] = sm;
    }
    __syncthreads();
    int ox = tid & 31, oy0 = (tid >> 5) << 2;
    float tmn = FLT_MAX, tmx = -FLT_MAX;
    #pragma unroll
    for (int j = 0; j < 4; ++j) {
        int oy = oy0 + j;
        float so = 0.f, sm = 0.f;
        #pragma unroll
        for (int d = 0; d < 9; ++d) { so += rs_o[oy + d][ox]; sm += rs_m[oy + d][ox]; }
        float p = (so * (1.f / 81.f)) * (sm * (1.f / 81.f));
        prod[(b * HH + ty0 + oy) * WW + tx0 + ox] = p;
        tmn = fminf(tmn, p); tmx = fmaxf(tmx, p);
    }
    __shared__ float smn[256], smx[256];
    smn[tid] = tmn; smx[tid] = tmx;
    __syncthreads();
    for (int off = 128; off > 0; off >>= 1) {
        if (tid < off) { smn[tid] = fminf(smn[tid], smn[tid + off]); smx[tid] = fmaxf(smx[tid], smx[tid + off]); }
        __syncthreads();
    }
    if (tid == 0) { pmn[blk] = smn[0]; pmx[blk] = smx[0]; }
}

__global__ void k_nms(const float* __restrict__ vsm, const float* __restrict__ prod,
                      const float* __restrict__ pmn, const float* __restrict__ pmx,
                      unsigned* __restrict__ bcnt, float* __restrict__ candV,
                      int* __restrict__ candI) {
    int blk = blockIdx.x;
    int b = blk >> 6, t = blk & 63;
    int ty0 = (t >> 3) << 5, tx0 = (t & 7) << 5;
    int tid = threadIdx.x;
    __shared__ float sred[2];
    if (tid < 64) {
        float mn = pmn[b * NTIL + tid];
        float mx = pmx[b * NTIL + tid];
        #pragma unroll
        for (int o = 32; o > 0; o >>= 1) { mn = fminf(mn, __shfl_xor(mn, o, 64)); mx = fmaxf(mx, __shfl_xor(mx, o, 64)); }
        if (tid == 0) { sred[0] = mn; sred[1] = mx; }
    }
    __syncthreads();
    float mnp = sred[0];
    float inv = 1.f / (sred[1] - mnp + 1e-6f);
    __shared__ float sc[36][36];
    __shared__ float hm[36][32];
    for (int i = tid; i < 1296; i += 256) {
        int ly = i / 36, lx = i - ly * 36;
        int gy = ty0 - 2 + ly, gx = tx0 - 2 + lx;
        float s = -FLT_MAX;
        if (gy >= 0 && gy < HH && gx >= 0 && gx < WW) {
            int idx = (b * HH + gy) * WW + gx;
            s = vsm[idx] * ((prod[idx] - mnp) * inv);
        }
        sc[ly][lx] = s;
    }
    __syncthreads();
    for (int i = tid; i < 1152; i += 256) {
        int ly = i >> 5, lx = i & 31;
        float m = sc[ly][lx];
        #pragma unroll
        for (int d = 1; d < 5; ++d) m = fmaxf(m, sc[ly][lx + d]);
        hm[ly][lx] = m;
    }
    __syncthreads();
    __shared__ unsigned scnt;
    __shared__ float bv[TCAP];
    __shared__ int bi[TCAP];
    if (tid == 0) scnt = 0;
    __syncthreads();
    int ox = tid & 31, oy0 = (tid >> 5) << 2;
    #pragma unroll
    for (int j = 0; j < 4; ++j) {
        int oy = oy0 + j;
        float m = hm[oy][ox];
        #pragma unroll
        for (int d = 1; d < 5; ++d) m = fmaxf(m, hm[oy + d][ox]);
        float s = sc[oy + 2][ox + 2];
        if (s == m && s > 0.f) {
            unsigned p = atomicAdd(&scnt, 1u);
            if (p < TCAP) { bv[p] = s; bi[p] = (ty0 + oy) * WW + tx0 + ox; }
        }
    }
    __syncthreads();
    unsigned cnt = min(scnt, (unsigned)TCAP);
    if (tid == 0) bcnt[blk] = cnt;
    for (unsigned i = tid; i < cnt; i += 256) {
        candV[blk * TCAP + i] = bv[i];
        candI[blk * TCAP + i] = bi[i];
    }
}

__global__ void __launch_bounds__(1024)
k_topk(const float* __restrict__ depth, const unsigned* __restrict__ bcnt,
       const float* __restrict__ candV, const int* __restrict__ candI,
       float4* __restrict__ pk) {
    int b = blockIdx.x;
    int tid = threadIdx.x;
    __shared__ unsigned hist[SELBINS];
    __shared__ unsigned sc[1024];
    __shared__ ull keyAll[SELCAP];
    __shared__ unsigned bcs[NTIL];
    __shared__ int sBin;
    __shared__ unsigned sN;
    const float* cv = candV + b * NTIL * TCAP;
    const int* ci = candI + b * NTIL * TCAP;
    #pragma unroll
    for (int i = 0; i < SELBINS / 1024; ++i) hist[tid + i * 1024] = 0;
    if (tid < NTIL) bcs[tid] = bcnt[b * NTIL + tid];
    if (tid == 0) { sBin = 0; sN = 0; }
    __syncthreads();
    for (int i = tid; i < NTIL * TCAP; i += 1024) {
        int tile = i >> 7, o = i & (TCAP - 1);
        if ((unsigned)o < bcs[tile]) atomicAdd(&hist[__float_as_uint(cv[i]) >> 19], 1u);
    }
    __syncthreads();
    int j0 = tid * 4;
    unsigned h0 = hist[j0], h1 = hist[j0 + 1], h2 = hist[j0 + 2], h3 = hist[j0 + 3];
    unsigned part = h0 + h1 + h2 + h3;
    sc[tid] = part;
    __syncthreads();
    for (int off = 1; off < 1024; off <<= 1) {
        unsigned v = (tid + off < 1024) ? sc[tid + off] : 0u;
        __syncthreads();
        sc[tid] += v;
        __syncthreads();
    }
    unsigned excl = sc[tid] - part;
    unsigned suf3 = excl + h3, suf2 = suf3 + h2, suf1 = suf2 + h1, suf0 = suf1 + h0;
    if (suf0 >= KTOP && suf0 - h0 < KTOP) sBin = j0;
    if (suf1 >= KTOP && suf1 - h1 < KTOP) sBin = j0 + 1;
    if (suf2 >= KTOP && suf2 - h2 < KTOP) sBin = j0 + 2;
    if (suf3 >= KTOP && suf3 - h3 < KTOP) sBin = j0 + 3;
    __syncthreads();
    int B = sBin;
    for (int i = tid; i < NTIL * TCAP; i += 1024) {
        int tile = i >> 7, o = i & (TCAP - 1);
        if ((unsigned)o < bcs[tile]) {
            unsigned bits = __float_as_uint(cv[i]);
            if ((int)(bits >> 19) >= B) {
                unsigned p = atomicAdd(&sN, 1u);
                if (p < SELCAP) keyAll[p] = ((ull)bits << 32) | (ull)(0xFFFFFFFFu - (unsigned)ci[i]);
            }
        }
    }
    __syncthreads();
    unsigned n = min(sN, (unsigned)SELCAP);
    unsigned P = 128; while (P < n) P <<= 1;
    for (unsigned i = n + tid; i < P; i += 1024) keyAll[i] = 0ull;
    __syncthreads();
    for (unsigned k = 2; k <= P; k <<= 1) {
        for (unsigned j = k >> 1; j > 0; j >>= 1) {
            for (unsigned i = tid; i < P; i += 1024) {
                unsigned ixj = i ^ j;
                if (ixj > i) {
                    ull a = keyAll[i], c = keyAll[ixj];
                    bool up = ((i & k) == 0);
                    if (up ? (a > c) : (a < c)) { keyAll[i] = c; keyAll[ixj] = a; }
                }
            }
            __syncthreads();
        }
    }
    if (tid < KTOP) {
        unsigned K = min((unsigned)KTOP, n);
        float plog = -INFINITY, fx = 0.f, fy = 0.f, c = 0.f;
        if ((unsigned)tid < K) {
            ull key = keyAll[P - 1 - tid];
            unsigned bits = (unsigned)(key >> 32);
            int idx = (int)(0xFFFFFFFFu - (unsigned)(key & 0xFFFFFFFFu));
            float val = __uint_as_float(bits);
            plog = log2f(val);
            fx = (float)(idx & 255);
            fy = (float)(idx >> 8);
            float z = fmaxf(depth[b * NPIX + idx], 0.001f);
            float r = fminf(fmaxf(14.f / z, 1.5f), 18.f);
            float s2 = 0.36f * r * r;
            c = 1.44269504f / (2.f * s2 + 1e-6f);
        }
        pk[b * KTOP + tid] = make_float4(plog, fx, fy, c);
    }
}

__global__ void k_splat(const float4* __restrict__ pk, float* __restrict__ gauss,
                        float* __restrict__ gmn, float* __restrict__ gmx) {
    int blk = blockIdx.x;
    int b = blk >> 6;
    int y0 = (blk & 63) << 2;
    int x = threadIdx.x;
    __shared__ float4 lp[KTOP];
    if (x < KTOP) lp[x] = pk[b * KTOP + x];
    __syncthreads();
    float fx = (float)x, fy = (float)y0;
    float g0 = -INFINITY, g1 = -INFINITY, g2 = -INFINITY, g3 = -INFINITY;
    #pragma unroll 4
    for (int k = 0; k < KTOP; ++k) {
        float4 q = lp[k];
        float dx = fx - q.y;
        float dx2 = dx * dx;
        float dy = fy - q.z;
        float d2;
        d2 = fmaf(dy, dy, dx2);        g0 = fmaxf(g0, fmaf(-d2, q.w, q.x));
        float dyb = dy + 1.f;
        d2 = fmaf(dyb, dyb, dx2);      g1 = fmaxf(g1, fmaf(-d2, q.w, q.x));
        float dyc = dy + 2.f;
        d2 = fmaf(dyc, dyc, dx2);      g2 = fmaxf(g2, fmaf(-d2, q.w, q.x));
        float dyd = dy + 3.f;
        d2 = fmaf(dyd, dyd, dx2);      g3 = fmaxf(g3, fmaf(-d2, q.w, q.x));
    }
    float v0 = exp2f(g0), v1 = exp2f(g1), v2 = exp2f(g2), v3 = exp2f(g3);
    int base = (b * HH + y0) * WW + x;
    gauss[base] = v0; gauss[base + WW] = v1; gauss[base + 2 * WW] = v2; gauss[base + 3 * WW] = v3;
    float tmn = fminf(fminf(v0, v1), fminf(v2, v3));
    float tmx = fmaxf(fmaxf(v0, v1), fmaxf(v2, v3));
    __shared__ float smn[256], smx[256];
    smn[x] = tmn; smx[x] = tmx;
    __syncthreads();
    for (int off = 128; off > 0; off >>= 1) {
        if (x < off) { smn[x] = fminf(smn[x], smn[x + off]); smx[x] = fmaxf(smx[x], smx[x + off]); }
        __syncthreads();
    }
    if (x == 0) { gmn[blk] = smn[0]; gmx[blk] = smx[0]; }
}

__global__ void k_norm(const float* __restrict__ gauss, const float* __restrict__ gmn,
                       const float* __restrict__ gmx, float* __restrict__ out) {
    int blk = blockIdx.x;
    int b = blk >> 6;
    int tid = threadIdx.x;
    __shared__ float sred[2];
    if (tid < 64) {
        float mn = gmn[b * NTIL + tid];
        float mx = gmx[b * NTIL + tid];
        #pragma unroll
        for (int o = 32; o > 0; o >>= 1) { mn = fminf(mn, __shfl_xor(mn, o, 64)); mx = fmaxf(mx, __shfl_xor(mx, o, 64)); }
        if (tid == 0) { sred[0] = mn; sred[1] = mx; }
    }
    __syncthreads();
    float mn = sred[0];
    float inv = 1.f / (sred[1] - mn + 1e-6f);
    int i = blk * 256 + tid;
    float4 v = ((const float4*)gauss)[i];
    v.x = (v.x - mn) * inv;
    v.y = (v.y - mn) * inv;
    v.z = (v.z - mn) * inv;
    v.w = (v.w - mn) * inv;
    ((float4*)out)[i] = v;
}

extern "C" void kernel_launch(void* const* d_in, const int* in_sizes, int n_in,
                              void* d_out, int out_size, void* d_ws, size_t ws_size,
                              hipStream_t stream) {
    const float* vsm   = (const float*)d_in[0];
    const float* depth = (const float*)d_in[1];
    float* out = (float*)d_out;
    char* ws = (char*)d_ws;

    // zero the barrier counters every call (also heals the 0xAA poison)
    hipMemsetAsync(ws, 0, BB * NBAR * BARSTRIDE * 4, stream);

    void* kargs[] = { (void*)&vsm, (void*)&depth, (void*)&out, (void*)&ws };
    hipError_t err = hipLaunchCooperativeKernel((const void*)k_mega, dim3(NBLK), dim3(256),
                                                kargs, 0, stream);
    if (err == hipSuccess) return;

    // fallback: proven 5-kernel pipeline (identical math / outputs)
    float4* pk = (float4*)(ws + BB * NBAR * BARSTRIDE * 4);
    float* prod = (float*)(pk + BB * KTOP);
    float* gauss = prod + TOT;
    float* pmn = gauss + TOT;
    float* pmx = pmn + NBLK;
    float* gmn = pmx + NBLK;
    float* gmx = gmn + NBLK;
    unsigned* bcnt = (unsigned*)(gmx + NBLK);
    float* candV = (float*)(bcnt + NBLK);
    int* candI = (int*)(candV + NBLK * TCAP);

    k_box9 <<<NBLK, 256, 0, stream>>>(vsm, prod, pmn, pmx);
    k_nms  <<<NBLK, 256, 0, stream>>>(vsm, prod, pmn, pmx, bcnt, candV, candI);
    k_topk <<<BB, 1024, 0, stream>>>(depth, bcnt, candV, candI, pk);
    k_splat<<<NBLK, 256, 0, stream>>>(pk, gauss, gmn, gmx);
    k_norm <<<NBLK, 256, 0, stream>>>(gauss, gmn, gmx, out);
}

// Round 7
// 57.674 us; speedup vs baseline: 4.5769x; 2.0425x over previous
//
#include <hip/hip_runtime.h>
#include <float.h>
#include <math.h>

#define BB 8
#define HH 256
#define WW 256
#define NPIX 65536          // HH*WW
#define TOT (BB*NPIX)
#define KTOP 80
#define NTIL 64             // 8x8 tiles of 32x32 per image
#define TCAP 128            // max candidates kept per tile
#define SELBINS 4096
#define SELCAP 2048
#define NBLK (BB*NTIL)      // 512
typedef unsigned long long ull;

// ============ fused 9x9 avg-pools -> prod, per-block min/max partials ============
__global__ void k_box9(const float* __restrict__ vsm, float* __restrict__ prod,
                       float* __restrict__ pmn, float* __restrict__ pmx) {
    int blk = blockIdx.x;
    int b = blk >> 6, t = blk & 63;
    int ty0 = (t >> 3) << 5, tx0 = (t & 7) << 5;
    int tid = threadIdx.x;
    __shared__ float val[40][40];
    __shared__ float rs_o[40][32];
    __shared__ float rs_m[40][32];
    for (int i = tid; i < 1600; i += 256) {
        int ly = i / 40, lx = i - ly * 40;
        int gy = ty0 - 4 + ly, gx = tx0 - 4 + lx;
        float v = 0.f;
        if (gy >= 0 && gy < HH && gx >= 0 && gx < WW) v = vsm[(b * HH + gy) * WW + gx];
        val[ly][lx] = v;
    }
    __syncthreads();
    for (int i = tid; i < 1280; i += 256) {
        int ly = i >> 5, lx = i & 31;
        float so = 0.f, sm = 0.f;
        #pragma unroll
        for (int d = 0; d < 9; ++d) { float v = val[ly][lx + d]; so += (v > 0.2f) ? 1.f : 0.f; sm += v; }
        rs_o[ly][lx] = so; rs_m[ly][lx] = sm;
    }
    __syncthreads();
    int ox = tid & 31, oy0 = (tid >> 5) << 2;
    float tmn = FLT_MAX, tmx = -FLT_MAX;
    #pragma unroll
    for (int j = 0; j < 4; ++j) {
        int oy = oy0 + j;
        float so = 0.f, sm = 0.f;
        #pragma unroll
        for (int d = 0; d < 9; ++d) { so += rs_o[oy + d][ox]; sm += rs_m[oy + d][ox]; }
        float p = (so * (1.f / 81.f)) * (sm * (1.f / 81.f));
        prod[(b * HH + ty0 + oy) * WW + tx0 + ox] = p;
        tmn = fminf(tmn, p); tmx = fmaxf(tmx, p);
    }
    __shared__ float smn[256], smx[256];
    smn[tid] = tmn; smx[tid] = tmx;
    __syncthreads();
    for (int off = 128; off > 0; off >>= 1) {
        if (tid < off) { smn[tid] = fminf(smn[tid], smn[tid + off]); smx[tid] = fmaxf(smx[tid], smx[tid + off]); }
        __syncthreads();
    }
    if (tid == 0) { pmn[blk] = smn[0]; pmx[blk] = smx[0]; }
}

// ============ score + 5x5 NMS + per-tile candidate compaction ============
__global__ void k_nms(const float* __restrict__ vsm, const float* __restrict__ prod,
                      const float* __restrict__ pmn, const float* __restrict__ pmx,
                      unsigned* __restrict__ bcnt, float* __restrict__ candV,
                      int* __restrict__ candI) {
    int blk = blockIdx.x;
    int b = blk >> 6, t = blk & 63;
    int ty0 = (t >> 3) << 5, tx0 = (t & 7) << 5;
    int tid = threadIdx.x;
    __shared__ float sred[2];
    if (tid < 64) {
        float mn = pmn[b * NTIL + tid];
        float mx = pmx[b * NTIL + tid];
        #pragma unroll
        for (int o = 32; o > 0; o >>= 1) { mn = fminf(mn, __shfl_xor(mn, o, 64)); mx = fmaxf(mx, __shfl_xor(mx, o, 64)); }
        if (tid == 0) { sred[0] = mn; sred[1] = mx; }
    }
    __syncthreads();
    float mnp = sred[0];
    float inv = 1.f / (sred[1] - mnp + 1e-6f);
    __shared__ float sc[36][36];
    __shared__ float hm[36][32];
    for (int i = tid; i < 1296; i += 256) {
        int ly = i / 36, lx = i - ly * 36;
        int gy = ty0 - 2 + ly, gx = tx0 - 2 + lx;
        float s = -FLT_MAX;
        if (gy >= 0 && gy < HH && gx >= 0 && gx < WW) {
            int idx = (b * HH + gy) * WW + gx;
            s = vsm[idx] * ((prod[idx] - mnp) * inv);
        }
        sc[ly][lx] = s;
    }
    __syncthreads();
    for (int i = tid; i < 1152; i += 256) {
        int ly = i >> 5, lx = i & 31;
        float m = sc[ly][lx];
        #pragma unroll
        for (int d = 1; d < 5; ++d) m = fmaxf(m, sc[ly][lx + d]);
        hm[ly][lx] = m;
    }
    __syncthreads();
    __shared__ unsigned scnt;
    __shared__ float bv[TCAP];
    __shared__ int bi[TCAP];
    if (tid == 0) scnt = 0;
    __syncthreads();
    int ox = tid & 31, oy0 = (tid >> 5) << 2;
    #pragma unroll
    for (int j = 0; j < 4; ++j) {
        int oy = oy0 + j;
        float m = hm[oy][ox];
        #pragma unroll
        for (int d = 1; d < 5; ++d) m = fmaxf(m, hm[oy + d][ox]);
        float s = sc[oy + 2][ox + 2];
        if (s == m && s > 0.f) {
            unsigned p = atomicAdd(&scnt, 1u);
            if (p < TCAP) { bv[p] = s; bi[p] = (ty0 + oy) * WW + tx0 + ox; }
        }
    }
    __syncthreads();
    unsigned cnt = min(scnt, (unsigned)TCAP);
    if (tid == 0) bcnt[blk] = cnt;
    for (unsigned i = tid; i < cnt; i += 256) {
        candV[blk * TCAP + i] = bv[i];
        candI[blk * TCAP + i] = bi[i];
    }
}

// ============ redundant per-block top-80 + log-domain splat (fused, no topk dispatch) ============
__global__ void __launch_bounds__(256)
k_splatk(const float* __restrict__ depth, const unsigned* __restrict__ bcnt,
         const float* __restrict__ candV, const int* __restrict__ candI,
         float* __restrict__ gauss, float* __restrict__ gmn, float* __restrict__ gmx) {
    int blk = blockIdx.x;            // b*64 + strip
    int b = blk >> 6;
    int tid = threadIdx.x;

    __shared__ struct {
        unsigned hist[SELBINS];
        ull keyAll[SELCAP];
        unsigned bcs[NTIL];
        unsigned scan[256];
    } tk;                                            // 34048 B
    __shared__ float4 lp[KTOP];
    __shared__ float r0[256], r1[256];
    __shared__ int sBin;
    __shared__ unsigned sN;

    // ---- per-block (redundant) exact top-80 of this batch -> lp[] ----
    {
        const float* cv = candV + b * NTIL * TCAP;
        const int*   ci = candI + b * NTIL * TCAP;
        for (int i = tid; i < SELBINS; i += 256) tk.hist[i] = 0;
        if (tid < NTIL) tk.bcs[tid] = bcnt[b * NTIL + tid];
        if (tid == 0) { sBin = 0; sN = 0; }
        __syncthreads();

        // histogram of float-bit bins (positive floats: bit order == value order)
        for (int i = tid; i < NTIL * TCAP; i += 256) {
            int tile = i >> 7, o = i & (TCAP - 1);
            if ((unsigned)o < tk.bcs[tile])
                atomicAdd(&tk.hist[__float_as_uint(cv[i]) >> 19], 1u);
        }
        __syncthreads();

        // suffix scan (16 bins/thread) -> boundary bin B with suffix(B) >= KTOP
        int j0 = tid * 16;
        unsigned part = 0;
        #pragma unroll
        for (int j = 0; j < 16; ++j) part += tk.hist[j0 + j];
        tk.scan[tid] = part;
        __syncthreads();
        for (int off = 1; off < 256; off <<= 1) {
            unsigned v = (tid + off < 256) ? tk.scan[tid + off] : 0u;
            __syncthreads();
            tk.scan[tid] += v;
            __syncthreads();
        }
        unsigned run = tk.scan[tid] - part;     // suffix sum of threads above
        for (int j = 15; j >= 0; --j) {
            unsigned h = tk.hist[j0 + j];
            run += h;                           // run == suffix(j0+j)
            if (run >= KTOP && run - h < KTOP) sBin = j0 + j;
        }
        __syncthreads();

        // collect keys in bins >= B (key = valbits:~idx -> desc val, asc idx)
        int B = sBin;
        for (int i = tid; i < NTIL * TCAP; i += 256) {
            int tile = i >> 7, o = i & (TCAP - 1);
            if ((unsigned)o < tk.bcs[tile]) {
                unsigned bits = __float_as_uint(cv[i]);
                if ((int)(bits >> 19) >= B) {
                    unsigned p = atomicAdd(&sN, 1u);
                    if (p < SELCAP)
                        tk.keyAll[p] = ((ull)bits << 32) | (ull)(0xFFFFFFFFu - (unsigned)ci[i]);
                }
            }
        }
        __syncthreads();
        unsigned n = min(sN, (unsigned)SELCAP);
        unsigned P = 128; while (P < n) P <<= 1;
        for (unsigned i = n + tid; i < P; i += 256) tk.keyAll[i] = 0ull;
        __syncthreads();

        // bitonic sort ascending; winners are the top (last) K entries
        for (unsigned k = 2; k <= P; k <<= 1) {
            for (unsigned j = k >> 1; j > 0; j >>= 1) {
                for (unsigned i = tid; i < P; i += 256) {
                    unsigned ixj = i ^ j;
                    if (ixj > i) {
                        ull a = tk.keyAll[i], c = tk.keyAll[ixj];
                        bool up = ((i & k) == 0);
                        if (up ? (a > c) : (a < c)) { tk.keyAll[i] = c; tk.keyAll[ixj] = a; }
                    }
                }
                __syncthreads();
            }
        }

        // emit packed peak params into LDS: {log2(val), x, y, c}
        if (tid < KTOP) {
            unsigned K = min((unsigned)KTOP, n);
            float plog = -INFINITY, fx = 0.f, fy = 0.f, c = 0.f;
            if ((unsigned)tid < K) {
                ull key = tk.keyAll[P - 1 - tid];
                unsigned bits = (unsigned)(key >> 32);
                int idx = (int)(0xFFFFFFFFu - (unsigned)(key & 0xFFFFFFFFu));
                float val = __uint_as_float(bits);
                plog = log2f(val);
                fx = (float)(idx & 255);
                fy = (float)(idx >> 8);
                float z = fmaxf(depth[b * NPIX + idx], 0.001f);
                float r = fminf(fmaxf(14.f / z, 1.5f), 18.f);
                float s2 = 0.36f * r * r;                     // (0.6*r)^2
                c = 1.44269504f / (2.f * s2 + 1e-6f);         // log2(e)/denom
            }
            lp[tid] = make_float4(plog, fx, fy, c);
        }
        __syncthreads();
    }

    // ---- log-domain gaussian splat: 4 rows/block, 4 px/thread, 1 exp2/px ----
    {
        int y0 = (blk & 63) << 2;
        float fx = (float)tid;
        float fy = (float)y0;
        float g0 = -INFINITY, g1 = -INFINITY, g2 = -INFINITY, g3 = -INFINITY;
        #pragma unroll 4
        for (int k = 0; k < KTOP; ++k) {
            float4 q = lp[k];                // {plog, px, py, c}
            float dx = fx - q.y;
            float dx2 = dx * dx;
            float dy = fy - q.z;
            float d2;
            d2 = fmaf(dy, dy, dx2);          g0 = fmaxf(g0, fmaf(-d2, q.w, q.x));
            float dyb = dy + 1.f;
            d2 = fmaf(dyb, dyb, dx2);        g1 = fmaxf(g1, fmaf(-d2, q.w, q.x));
            float dyc = dy + 2.f;
            d2 = fmaf(dyc, dyc, dx2);        g2 = fmaxf(g2, fmaf(-d2, q.w, q.x));
            float dyd = dy + 3.f;
            d2 = fmaf(dyd, dyd, dx2);        g3 = fmaxf(g3, fmaf(-d2, q.w, q.x));
        }
        float v0 = exp2f(g0), v1 = exp2f(g1), v2 = exp2f(g2), v3 = exp2f(g3);
        int base = (b * HH + y0) * WW + tid;
        gauss[base]          = v0;
        gauss[base + WW]     = v1;
        gauss[base + 2 * WW] = v2;
        gauss[base + 3 * WW] = v3;

        float tmn = fminf(fminf(v0, v1), fminf(v2, v3));
        float tmx = fmaxf(fmaxf(v0, v1), fmaxf(v2, v3));
        r0[tid] = tmn; r1[tid] = tmx;
        __syncthreads();
        for (int off = 128; off > 0; off >>= 1) {
            if (tid < off) {
                r0[tid] = fminf(r0[tid], r0[tid + off]);
                r1[tid] = fmaxf(r1[tid], r1[tid + off]);
            }
            __syncthreads();
        }
        if (tid == 0) { gmn[blk] = r0[0]; gmx[blk] = r1[0]; }
    }
}

// ============ final norm01 (float4 vectorized) ============
__global__ void k_norm(const float* __restrict__ gauss, const float* __restrict__ gmn,
                       const float* __restrict__ gmx, float* __restrict__ out) {
    int blk = blockIdx.x;
    int b = blk >> 6;
    int tid = threadIdx.x;
    __shared__ float sred[2];
    if (tid < 64) {
        float mn = gmn[b * NTIL + tid];
        float mx = gmx[b * NTIL + tid];
        #pragma unroll
        for (int o = 32; o > 0; o >>= 1) { mn = fminf(mn, __shfl_xor(mn, o, 64)); mx = fmaxf(mx, __shfl_xor(mx, o, 64)); }
        if (tid == 0) { sred[0] = mn; sred[1] = mx; }
    }
    __syncthreads();
    float mn = sred[0];
    float inv = 1.f / (sred[1] - mn + 1e-6f);
    int i = blk * 256 + tid;
    float4 v = ((const float4*)gauss)[i];
    v.x = (v.x - mn) * inv;
    v.y = (v.y - mn) * inv;
    v.z = (v.z - mn) * inv;
    v.w = (v.w - mn) * inv;
    ((float4*)out)[i] = v;
}

extern "C" void kernel_launch(void* const* d_in, const int* in_sizes, int n_in,
                              void* d_out, int out_size, void* d_ws, size_t ws_size,
                              hipStream_t stream) {
    const float* vsm   = (const float*)d_in[0];
    const float* depth = (const float*)d_in[1];
    float* out = (float*)d_out;

    // workspace layout
    float* prod  = (float*)d_ws;                       // TOT
    float* gauss = prod + TOT;                         // TOT
    float* pmn   = gauss + TOT;                        // NBLK
    float* pmx   = pmn + NBLK;
    float* gmn   = pmx + NBLK;
    float* gmx   = gmn + NBLK;
    unsigned* bcnt = (unsigned*)(gmx + NBLK);          // NBLK
    float* candV = (float*)(bcnt + NBLK);              // NBLK*TCAP
    int*   candI = (int*)(candV + NBLK * TCAP);        // NBLK*TCAP

    k_box9  <<<NBLK, 256, 0, stream>>>(vsm, prod, pmn, pmx);
    k_nms   <<<NBLK, 256, 0, stream>>>(vsm, prod, pmn, pmx, bcnt, candV, candI);
    k_splatk<<<NBLK, 256, 0, stream>>>(depth, bcnt, candV, candI, gauss, gmn, gmx);
    k_norm  <<<NBLK, 256, 0, stream>>>(gauss, gmn, gmx, out);
}

// Round 8
// 46.784 us; speedup vs baseline: 5.6423x; 1.2328x over previous
//
#include <hip/hip_runtime.h>
#include <float.h>
#include <math.h>

#define BB 8
#define HH 256
#define WW 256
#define NPIX 65536          // HH*WW
#define TOT (BB*NPIX)
#define KTOP 80
#define NTIL 64             // 8x8 tiles of 32x32 per image
#define TCAP 128            // max candidates kept per tile (NMS spacing caps ~121)
#define SELBINS 4096
#define SELCAP 2048
#define NBLK (BB*NTIL)      // 512
typedef unsigned long long ull;

// ============ fused 9x9 avg-pools -> prod, per-block min/max partials; zero hist ============
__global__ void k_box9(const float* __restrict__ vsm, float* __restrict__ prod,
                       float* __restrict__ pmn, float* __restrict__ pmx,
                       unsigned* __restrict__ histg) {
    int blk = blockIdx.x;
    int b = blk >> 6, t = blk & 63;
    int ty0 = (t >> 3) << 5, tx0 = (t & 7) << 5;
    int tid = threadIdx.x;

    // zero this block's 64-bin slice of the batch histogram (512*64 = 8*4096)
    if (tid < 64) histg[b * SELBINS + t * 64 + tid] = 0u;

    __shared__ float val[40][40];
    __shared__ float rs_o[40][32];
    __shared__ float rs_m[40][32];
    for (int i = tid; i < 1600; i += 256) {
        int ly = i / 40, lx = i - ly * 40;
        int gy = ty0 - 4 + ly, gx = tx0 - 4 + lx;
        float v = 0.f;
        if (gy >= 0 && gy < HH && gx >= 0 && gx < WW) v = vsm[(b * HH + gy) * WW + gx];
        val[ly][lx] = v;
    }
    __syncthreads();
    for (int i = tid; i < 1280; i += 256) {
        int ly = i >> 5, lx = i & 31;
        float so = 0.f, sm = 0.f;
        #pragma unroll
        for (int d = 0; d < 9; ++d) { float v = val[ly][lx + d]; so += (v > 0.2f) ? 1.f : 0.f; sm += v; }
        rs_o[ly][lx] = so; rs_m[ly][lx] = sm;
    }
    __syncthreads();
    int ox = tid & 31, oy0 = (tid >> 5) << 2;
    float tmn = FLT_MAX, tmx = -FLT_MAX;
    #pragma unroll
    for (int j = 0; j < 4; ++j) {
        int oy = oy0 + j;
        float so = 0.f, sm = 0.f;
        #pragma unroll
        for (int d = 0; d < 9; ++d) { so += rs_o[oy + d][ox]; sm += rs_m[oy + d][ox]; }
        float p = (so * (1.f / 81.f)) * (sm * (1.f / 81.f));
        prod[(b * HH + ty0 + oy) * WW + tx0 + ox] = p;
        tmn = fminf(tmn, p); tmx = fmaxf(tmx, p);
    }
    __shared__ float smn[256], smx[256];
    smn[tid] = tmn; smx[tid] = tmx;
    __syncthreads();
    for (int off = 128; off > 0; off >>= 1) {
        if (tid < off) { smn[tid] = fminf(smn[tid], smn[tid + off]); smx[tid] = fmaxf(smx[tid], smx[tid + off]); }
        __syncthreads();
    }
    if (tid == 0) { pmn[blk] = smn[0]; pmx[blk] = smx[0]; }
}

// ============ score + 5x5 NMS + per-tile compaction + distributed histogram ============
__global__ void k_nms(const float* __restrict__ vsm, const float* __restrict__ prod,
                      const float* __restrict__ pmn, const float* __restrict__ pmx,
                      unsigned* __restrict__ bcnt, float* __restrict__ candV,
                      int* __restrict__ candI, unsigned* __restrict__ histg) {
    int blk = blockIdx.x;
    int b = blk >> 6, t = blk & 63;
    int ty0 = (t >> 3) << 5, tx0 = (t & 7) << 5;
    int tid = threadIdx.x;
    __shared__ float sred[2];
    if (tid < 64) {
        float mn = pmn[b * NTIL + tid];
        float mx = pmx[b * NTIL + tid];
        #pragma unroll
        for (int o = 32; o > 0; o >>= 1) { mn = fminf(mn, __shfl_xor(mn, o, 64)); mx = fmaxf(mx, __shfl_xor(mx, o, 64)); }
        if (tid == 0) { sred[0] = mn; sred[1] = mx; }
    }
    __syncthreads();
    float mnp = sred[0];
    float inv = 1.f / (sred[1] - mnp + 1e-6f);
    __shared__ float sc[36][36];
    __shared__ float hm[36][32];
    for (int i = tid; i < 1296; i += 256) {
        int ly = i / 36, lx = i - ly * 36;
        int gy = ty0 - 2 + ly, gx = tx0 - 2 + lx;
        float s = -FLT_MAX;
        if (gy >= 0 && gy < HH && gx >= 0 && gx < WW) {
            int idx = (b * HH + gy) * WW + gx;
            s = vsm[idx] * ((prod[idx] - mnp) * inv);
        }
        sc[ly][lx] = s;
    }
    __syncthreads();
    for (int i = tid; i < 1152; i += 256) {
        int ly = i >> 5, lx = i & 31;
        float m = sc[ly][lx];
        #pragma unroll
        for (int d = 1; d < 5; ++d) m = fmaxf(m, sc[ly][lx + d]);
        hm[ly][lx] = m;
    }
    __syncthreads();
    __shared__ unsigned scnt;
    __shared__ float bv[TCAP];
    __shared__ int bi[TCAP];
    if (tid == 0) scnt = 0;
    __syncthreads();
    int ox = tid & 31, oy0 = (tid >> 5) << 2;
    #pragma unroll
    for (int j = 0; j < 4; ++j) {
        int oy = oy0 + j;
        float m = hm[oy][ox];
        #pragma unroll
        for (int d = 1; d < 5; ++d) m = fmaxf(m, hm[oy + d][ox]);
        float s = sc[oy + 2][ox + 2];
        if (s == m && s > 0.f) {
            unsigned p = atomicAdd(&scnt, 1u);
            if (p < TCAP) { bv[p] = s; bi[p] = (ty0 + oy) * WW + tx0 + ox; }
        }
    }
    __syncthreads();
    unsigned cnt = min(scnt, (unsigned)TCAP);
    if (tid == 0) bcnt[blk] = cnt;
    for (unsigned i = tid; i < cnt; i += 256) {
        float v = bv[i];
        candV[blk * TCAP + i] = v;
        candI[blk * TCAP + i] = bi[i];
        // distributed per-batch histogram (scattered bins -> low contention)
        atomicAdd(&histg[b * SELBINS + (__float_as_uint(v) >> 19)], 1u);
    }
}

// ============ per-batch exact top-80: prebuilt histogram -> collect (unrolled) -> bitonic ============
__global__ void __launch_bounds__(1024)
k_topk(const float* __restrict__ depth, const unsigned* __restrict__ bcnt,
       const float* __restrict__ candV, const int* __restrict__ candI,
       const unsigned* __restrict__ histg, float4* __restrict__ pk) {
    int b = blockIdx.x;
    int tid = threadIdx.x;
    __shared__ unsigned sc[1024];
    __shared__ ull keyAll[SELCAP];
    __shared__ unsigned bcs[NTIL];
    __shared__ int sBin;
    __shared__ unsigned sN;
    const float* cv = candV + b * NTIL * TCAP;
    const int* ci = candI + b * NTIL * TCAP;

    if (tid < NTIL) bcs[tid] = bcnt[b * NTIL + tid];
    if (tid == 0) { sBin = 0; sN = 0; }

    // load prebuilt histogram: 4 bins/thread (one dwordx4-able stretch)
    int j0 = tid * 4;
    const unsigned* hg = histg + b * SELBINS;
    unsigned h0 = hg[j0], h1 = hg[j0 + 1], h2 = hg[j0 + 2], h3 = hg[j0 + 3];
    unsigned part = h0 + h1 + h2 + h3;
    sc[tid] = part;
    __syncthreads();
    for (int off = 1; off < 1024; off <<= 1) {
        unsigned v = (tid + off < 1024) ? sc[tid + off] : 0u;
        __syncthreads();
        sc[tid] += v;
        __syncthreads();
    }
    unsigned excl = sc[tid] - part;        // sum over threads > tid
    unsigned suf3 = excl + h3, suf2 = suf3 + h2, suf1 = suf2 + h1, suf0 = suf1 + h0;
    if (suf0 >= KTOP && suf0 - h0 < KTOP) sBin = j0;
    if (suf1 >= KTOP && suf1 - h1 < KTOP) sBin = j0 + 1;
    if (suf2 >= KTOP && suf2 - h2 < KTOP) sBin = j0 + 2;
    if (suf3 >= KTOP && suf3 - h3 < KTOP) sBin = j0 + 3;
    __syncthreads();

    // collect keys in bins >= B; unrolled so all 8 loads are in flight together
    int B = sBin;
    float v[8]; bool ok[8];
    #pragma unroll
    for (int u = 0; u < 8; ++u) {
        int i = tid + u * 1024;
        ok[u] = (unsigned)(i & (TCAP - 1)) < bcs[i >> 7];
        v[u] = cv[i];                       // unconditional load; guarded by ok[]
    }
    #pragma unroll
    for (int u = 0; u < 8; ++u) {
        if (ok[u]) {
            unsigned bits = __float_as_uint(v[u]);
            if ((int)(bits >> 19) >= B) {
                int i = tid + u * 1024;
                unsigned p = atomicAdd(&sN, 1u);
                if (p < SELCAP)
                    keyAll[p] = ((ull)bits << 32) | (ull)(0xFFFFFFFFu - (unsigned)ci[i]);
            }
        }
    }
    __syncthreads();
    unsigned n = min(sN, (unsigned)SELCAP);
    unsigned P = 128; while (P < n) P <<= 1;
    for (unsigned i = n + tid; i < P; i += 1024) keyAll[i] = 0ull;
    __syncthreads();

    // bitonic sort ascending; winners are the top (last) K entries
    for (unsigned k = 2; k <= P; k <<= 1) {
        for (unsigned j = k >> 1; j > 0; j >>= 1) {
            for (unsigned i = tid; i < P; i += 1024) {
                unsigned ixj = i ^ j;
                if (ixj > i) {
                    ull a = keyAll[i], c = keyAll[ixj];
                    bool up = ((i & k) == 0);
                    if (up ? (a > c) : (a < c)) { keyAll[i] = c; keyAll[ixj] = a; }
                }
            }
            __syncthreads();
        }
    }

    // emit packed peak params: {log2(val), x, y, c}
    if (tid < KTOP) {
        unsigned K = min((unsigned)KTOP, n);
        float plog = -INFINITY, fx = 0.f, fy = 0.f, c = 0.f;
        if ((unsigned)tid < K) {
            ull key = keyAll[P - 1 - tid];
            unsigned bits = (unsigned)(key >> 32);
            int idx = (int)(0xFFFFFFFFu - (unsigned)(key & 0xFFFFFFFFu));
            float val = __uint_as_float(bits);
            plog = log2f(val);
            fx = (float)(idx & 255);
            fy = (float)(idx >> 8);
            float z = fmaxf(depth[b * NPIX + idx], 0.001f);
            float r = fminf(fmaxf(14.f / z, 1.5f), 18.f);
            float s2 = 0.36f * r * r;                     // (0.6*r)^2
            c = 1.44269504f / (2.f * s2 + 1e-6f);         // log2(e)/denom
        }
        pk[b * KTOP + tid] = make_float4(plog, fx, fy, c);
    }
}

// ============ log-domain gaussian splat: 4 px/thread, single exp2 per pixel ============
__global__ void k_splat(const float4* __restrict__ pk, float* __restrict__ gauss,
                        float* __restrict__ gmn, float* __restrict__ gmx) {
    int blk = blockIdx.x;
    int b = blk >> 6;
    int y0 = (blk & 63) << 2;
    int x = threadIdx.x;
    __shared__ float4 lp[KTOP];
    if (x < KTOP) lp[x] = pk[b * KTOP + x];
    __syncthreads();
    float fx = (float)x, fy = (float)y0;
    float g0 = -INFINITY, g1 = -INFINITY, g2 = -INFINITY, g3 = -INFINITY;
    #pragma unroll 4
    for (int k = 0; k < KTOP; ++k) {
        float4 q = lp[k];
        float dx = fx - q.y;
        float dx2 = dx * dx;
        float dy = fy - q.z;
        float d2;
        d2 = fmaf(dy, dy, dx2);        g0 = fmaxf(g0, fmaf(-d2, q.w, q.x));
        float dyb = dy + 1.f;
        d2 = fmaf(dyb, dyb, dx2);      g1 = fmaxf(g1, fmaf(-d2, q.w, q.x));
        float dyc = dy + 2.f;
        d2 = fmaf(dyc, dyc, dx2);      g2 = fmaxf(g2, fmaf(-d2, q.w, q.x));
        float dyd = dy + 3.f;
        d2 = fmaf(dyd, dyd, dx2);      g3 = fmaxf(g3, fmaf(-d2, q.w, q.x));
    }
    float v0 = exp2f(g0), v1 = exp2f(g1), v2 = exp2f(g2), v3 = exp2f(g3);
    int base = (b * HH + y0) * WW + x;
    gauss[base] = v0; gauss[base + WW] = v1; gauss[base + 2 * WW] = v2; gauss[base + 3 * WW] = v3;
    float tmn = fminf(fminf(v0, v1), fminf(v2, v3));
    float tmx = fmaxf(fmaxf(v0, v1), fmaxf(v2, v3));
    __shared__ float smn[256], smx[256];
    smn[x] = tmn; smx[x] = tmx;
    __syncthreads();
    for (int off = 128; off > 0; off >>= 1) {
        if (x < off) { smn[x] = fminf(smn[x], smn[x + off]); smx[x] = fmaxf(smx[x], smx[x + off]); }
        __syncthreads();
    }
    if (x == 0) { gmn[blk] = smn[0]; gmx[blk] = smx[0]; }
}

// ============ final norm01 (float4 vectorized) ============
__global__ void k_norm(const float* __restrict__ gauss, const float* __restrict__ gmn,
                       const float* __restrict__ gmx, float* __restrict__ out) {
    int blk = blockIdx.x;
    int b = blk >> 6;
    int tid = threadIdx.x;
    __shared__ float sred[2];
    if (tid < 64) {
        float mn = gmn[b * NTIL + tid];
        float mx = gmx[b * NTIL + tid];
        #pragma unroll
        for (int o = 32; o > 0; o >>= 1) { mn = fminf(mn, __shfl_xor(mn, o, 64)); mx = fmaxf(mx, __shfl_xor(mx, o, 64)); }
        if (tid == 0) { sred[0] = mn; sred[1] = mx; }
    }
    __syncthreads();
    float mn = sred[0];
    float inv = 1.f / (sred[1] - mn + 1e-6f);
    int i = blk * 256 + tid;
    float4 v = ((const float4*)gauss)[i];
    v.x = (v.x - mn) * inv;
    v.y = (v.y - mn) * inv;
    v.z = (v.z - mn) * inv;
    v.w = (v.w - mn) * inv;
    ((float4*)out)[i] = v;
}

extern "C" void kernel_launch(void* const* d_in, const int* in_sizes, int n_in,
                              void* d_out, int out_size, void* d_ws, size_t ws_size,
                              hipStream_t stream) {
    const float* vsm   = (const float*)d_in[0];
    const float* depth = (const float*)d_in[1];
    float* out = (float*)d_out;

    // workspace layout (pk first for 16B alignment)
    float4* pk   = (float4*)d_ws;                      // BB*KTOP
    float* prod  = (float*)(pk + BB * KTOP);           // TOT
    float* gauss = prod + TOT;                         // TOT
    float* pmn   = gauss + TOT;                        // NBLK
    float* pmx   = pmn + NBLK;
    float* gmn   = pmx + NBLK;
    float* gmx   = gmn + NBLK;
    unsigned* bcnt  = (unsigned*)(gmx + NBLK);         // NBLK
    unsigned* histg = bcnt + NBLK;                     // BB*SELBINS
    float* candV = (float*)(histg + BB * SELBINS);     // NBLK*TCAP
    int*   candI = (int*)(candV + NBLK * TCAP);        // NBLK*TCAP

    k_box9 <<<NBLK, 256, 0, stream>>>(vsm, prod, pmn, pmx, histg);
    k_nms  <<<NBLK, 256, 0, stream>>>(vsm, prod, pmn, pmx, bcnt, candV, candI, histg);
    k_topk <<<BB, 1024, 0, stream>>>(depth, bcnt, candV, candI, histg, pk);
    k_splat<<<NBLK, 256, 0, stream>>>(pk, gauss, gmn, gmx);
    k_norm <<<NBLK, 256, 0, stream>>>(gauss, gmn, gmx, out);
}

// Round 9
// 46.318 us; speedup vs baseline: 5.6991x; 1.0101x over previous
//
#include <hip/hip_runtime.h>
#include <float.h>
#include <math.h>

#define BB 8
#define HH 256
#define WW 256
#define NPIX 65536          // HH*WW
#define TOT (BB*NPIX)
#define KTOP 80
#define NTIL 64             // 8x8 tiles of 32x32 per image
#define TCAP 128            // max peaks per 32x32 tile (5x5 NMS spacing caps ~121)
#define CAP 8192            // max candidates per batch
#define SELBINS 4096
#define BNDCAP 1024
#define NBLK (BB*NTIL)      // 512
typedef unsigned long long ull;

// ============ fused 9x9 avg-pools -> prod, per-block min/max partials; zero hist+bcnt ============
__global__ void k_box9(const float* __restrict__ vsm, float* __restrict__ prod,
                       float* __restrict__ pmn, float* __restrict__ pmx,
                       unsigned* __restrict__ histg, unsigned* __restrict__ bcnt) {
    int blk = blockIdx.x;
    int b = blk >> 6, t = blk & 63;
    int ty0 = (t >> 3) << 5, tx0 = (t & 7) << 5;
    int tid = threadIdx.x;

    // zero this block's 64-bin slice of the batch histogram; blocks 0..7 zero batch counters
    if (tid < 64) histg[b * SELBINS + t * 64 + tid] = 0u;
    if (blk < BB && tid == 0) bcnt[blk] = 0u;

    __shared__ float val[40][40];
    __shared__ float rs_o[40][32];
    __shared__ float rs_m[40][32];
    for (int i = tid; i < 1600; i += 256) {
        int ly = i / 40, lx = i - ly * 40;
        int gy = ty0 - 4 + ly, gx = tx0 - 4 + lx;
        float v = 0.f;
        if (gy >= 0 && gy < HH && gx >= 0 && gx < WW) v = vsm[(b * HH + gy) * WW + gx];
        val[ly][lx] = v;
    }
    __syncthreads();
    for (int i = tid; i < 1280; i += 256) {
        int ly = i >> 5, lx = i & 31;
        float so = 0.f, sm = 0.f;
        #pragma unroll
        for (int d = 0; d < 9; ++d) { float v = val[ly][lx + d]; so += (v > 0.2f) ? 1.f : 0.f; sm += v; }
        rs_o[ly][lx] = so; rs_m[ly][lx] = sm;
    }
    __syncthreads();
    int ox = tid & 31, oy0 = (tid >> 5) << 2;
    float tmn = FLT_MAX, tmx = -FLT_MAX;
    #pragma unroll
    for (int j = 0; j < 4; ++j) {
        int oy = oy0 + j;
        float so = 0.f, sm = 0.f;
        #pragma unroll
        for (int d = 0; d < 9; ++d) { so += rs_o[oy + d][ox]; sm += rs_m[oy + d][ox]; }
        float p = (so * (1.f / 81.f)) * (sm * (1.f / 81.f));
        prod[(b * HH + ty0 + oy) * WW + tx0 + ox] = p;
        tmn = fminf(tmn, p); tmx = fmaxf(tmx, p);
    }
    __shared__ float smn[256], smx[256];
    smn[tid] = tmn; smx[tid] = tmx;
    __syncthreads();
    for (int off = 128; off > 0; off >>= 1) {
        if (tid < off) { smn[tid] = fminf(smn[tid], smn[tid + off]); smx[tid] = fmaxf(smx[tid], smx[tid + off]); }
        __syncthreads();
    }
    if (tid == 0) { pmn[blk] = smn[0]; pmx[blk] = smx[0]; }
}

// ============ score + 5x5 NMS + per-BATCH compact candidates + per-batch histogram ============
__global__ void k_nms(const float* __restrict__ vsm, const float* __restrict__ prod,
                      const float* __restrict__ pmn, const float* __restrict__ pmx,
                      unsigned* __restrict__ bcnt, float* __restrict__ candV,
                      int* __restrict__ candI, unsigned* __restrict__ histg) {
    int blk = blockIdx.x;
    int b = blk >> 6, t = blk & 63;
    int ty0 = (t >> 3) << 5, tx0 = (t & 7) << 5;
    int tid = threadIdx.x;
    __shared__ float sred[2];
    if (tid < 64) {
        float mn = pmn[b * NTIL + tid];
        float mx = pmx[b * NTIL + tid];
        #pragma unroll
        for (int o = 32; o > 0; o >>= 1) { mn = fminf(mn, __shfl_xor(mn, o, 64)); mx = fmaxf(mx, __shfl_xor(mx, o, 64)); }
        if (tid == 0) { sred[0] = mn; sred[1] = mx; }
    }
    __syncthreads();
    float mnp = sred[0];
    float inv = 1.f / (sred[1] - mnp + 1e-6f);
    __shared__ float sc[36][36];
    __shared__ float hm[36][32];
    for (int i = tid; i < 1296; i += 256) {
        int ly = i / 36, lx = i - ly * 36;
        int gy = ty0 - 2 + ly, gx = tx0 - 2 + lx;
        float s = -FLT_MAX;
        if (gy >= 0 && gy < HH && gx >= 0 && gx < WW) {
            int idx = (b * HH + gy) * WW + gx;
            s = vsm[idx] * ((prod[idx] - mnp) * inv);
        }
        sc[ly][lx] = s;
    }
    __syncthreads();
    for (int i = tid; i < 1152; i += 256) {
        int ly = i >> 5, lx = i & 31;
        float m = sc[ly][lx];
        #pragma unroll
        for (int d = 1; d < 5; ++d) m = fmaxf(m, sc[ly][lx + d]);
        hm[ly][lx] = m;
    }
    __syncthreads();
    __shared__ unsigned scnt;
    __shared__ unsigned sbase;
    __shared__ float bv[TCAP];
    __shared__ int bi[TCAP];
    if (tid == 0) scnt = 0;
    __syncthreads();
    int ox = tid & 31, oy0 = (tid >> 5) << 2;
    #pragma unroll
    for (int j = 0; j < 4; ++j) {
        int oy = oy0 + j;
        float m = hm[oy][ox];
        #pragma unroll
        for (int d = 1; d < 5; ++d) m = fmaxf(m, hm[oy + d][ox]);
        float s = sc[oy + 2][ox + 2];
        if (s == m && s > 0.f) {
            unsigned p = atomicAdd(&scnt, 1u);
            if (p < TCAP) { bv[p] = s; bi[p] = (ty0 + oy) * WW + tx0 + ox; }
        }
    }
    __syncthreads();
    unsigned cnt = min(scnt, (unsigned)TCAP);
    if (tid == 0) sbase = cnt ? atomicAdd(&bcnt[b], cnt) : 0u;   // ONE global atomic per tile
    __syncthreads();
    unsigned base = sbase;
    for (unsigned i = tid; i < cnt; i += 256) {
        unsigned pos = base + i;
        if (pos < CAP) {
            float v = bv[i];
            candV[b * CAP + pos] = v;
            candI[b * CAP + pos] = bi[i];
            atomicAdd(&histg[b * SELBINS + (__float_as_uint(v) >> 19)], 1u);
        }
    }
}

// ============ per-block top-80 SET (hist-scan + boundary-only sort) + log-domain splat ============
__global__ void __launch_bounds__(256)
k_tsplat(const float* __restrict__ depth, const unsigned* __restrict__ bcnt,
         const float* __restrict__ candV, const int* __restrict__ candI,
         const unsigned* __restrict__ histg,
         float* __restrict__ gauss, float* __restrict__ gmn, float* __restrict__ gmx) {
    int blk = blockIdx.x;
    int b = blk >> 6;
    int tid = threadIdx.x;

    __shared__ unsigned sscan[256];
    __shared__ ull acc[KTOP];        // bins > B (cntAbove < 80 by construction)
    __shared__ ull bnd[BNDCAP];      // boundary bin entries
    __shared__ float4 lp[KTOP];
    __shared__ float r0[256], r1[256];
    __shared__ int sB;
    __shared__ unsigned sAbove, nAccS, nBndS;

    int nC = min((int)bcnt[b], CAP);

    // ---- suffix-scan prebuilt histogram: find boundary bin B and count above ----
    {
        const unsigned* hg = histg + b * SELBINS;
        int j0 = tid * 16;
        unsigned h[16]; unsigned part = 0;
        #pragma unroll
        for (int j = 0; j < 16; ++j) { h[j] = hg[j0 + j]; part += h[j]; }
        if (tid == 0) { sB = -1; sAbove = 0; nAccS = 0; nBndS = 0; }
        sscan[tid] = part;
        __syncthreads();
        for (int off = 1; off < 256; off <<= 1) {
            unsigned v = (tid + off < 256) ? sscan[tid + off] : 0u;
            __syncthreads();
            sscan[tid] += v;
            __syncthreads();
        }
        unsigned run = sscan[tid] - part;        // suffix over threads > tid
        for (int j = 15; j >= 0; --j) {
            unsigned hj = h[j];
            run += hj;                           // run == suffix(j0+j)
            if (run >= KTOP && run - hj < KTOP) { sB = j0 + j; sAbove = run - hj; }
        }
        __syncthreads();
    }
    int B = sB;

    // ---- stream compact candidates: accept bins>B, stage boundary bin ----
    for (int i = tid; i < nC; i += 256) {
        float v = candV[b * CAP + i];
        int id = candI[b * CAP + i];
        unsigned bits = __float_as_uint(v);
        int bin = (int)(bits >> 19);
        ull key = ((ull)bits << 32) | (ull)(0xFFFFFFFFu - (unsigned)id);
        if (bin > B) {
            unsigned p = atomicAdd(&nAccS, 1u);
            if (p < KTOP) acc[p] = key;
        } else if (bin == B) {
            unsigned q = atomicAdd(&nBndS, 1u);
            if (q < BNDCAP) bnd[q] = key;
        }
    }
    __syncthreads();
    unsigned nAcc = min(nAccS, (unsigned)KTOP);
    unsigned nBnd = min(nBndS, (unsigned)BNDCAP);
    unsigned quota = (KTOP > nAcc) ? (KTOP - nAcc) : 0u;
    if (quota > nBnd) quota = nBnd;

    // ---- sort boundary bin only if it overfills the quota (desc: val desc, idx asc) ----
    if (nBnd > quota) {
        unsigned P = 2; while (P < nBnd) P <<= 1;
        for (unsigned i = nBnd + tid; i < P; i += 256) bnd[i] = 0ull;
        __syncthreads();
        for (unsigned k = 2; k <= P; k <<= 1) {
            for (unsigned j = k >> 1; j > 0; j >>= 1) {
                for (unsigned i = tid; i < P; i += 256) {
                    unsigned ixj = i ^ j;
                    if (ixj > i) {
                        ull a = bnd[i], c = bnd[ixj];
                        bool up = ((i & k) == 0);
                        if (up ? (a < c) : (a > c)) { bnd[i] = c; bnd[ixj] = a; }  // descending
                    }
                }
                __syncthreads();
            }
        }
    }
    __syncthreads();

    // ---- build packed peak params {log2(val), x, y, c} (order irrelevant: splat is a max) ----
    if (tid < KTOP) {
        ull key = 0ull;
        if ((unsigned)tid < nAcc) key = acc[tid];
        else if ((unsigned)tid < nAcc + quota) key = bnd[tid - nAcc];
        float plog = -INFINITY, fx = 0.f, fy = 0.f, c = 0.f;
        if (key) {
            unsigned bits = (unsigned)(key >> 32);
            int idx = (int)(0xFFFFFFFFu - (unsigned)(key & 0xFFFFFFFFu));
            float val = __uint_as_float(bits);
            plog = log2f(val);
            fx = (float)(idx & 255);
            fy = (float)(idx >> 8);
            float z = fmaxf(depth[b * NPIX + idx], 0.001f);
            float r = fminf(fmaxf(14.f / z, 1.5f), 18.f);
            float s2 = 0.36f * r * r;                     // (0.6*r)^2
            c = 1.44269504f / (2.f * s2 + 1e-6f);         // log2(e)/denom
        }
        lp[tid] = make_float4(plog, fx, fy, c);
    }
    __syncthreads();

    // ---- log-domain gaussian splat: 4 rows/block, 4 px/thread, 1 exp2/px ----
    {
        int y0 = (blk & 63) << 2;
        float fx = (float)tid;
        float fy = (float)y0;
        float g0 = -INFINITY, g1 = -INFINITY, g2 = -INFINITY, g3 = -INFINITY;
        #pragma unroll 4
        for (int k = 0; k < KTOP; ++k) {
            float4 q = lp[k];                // {plog, px, py, c}
            float dx = fx - q.y;
            float dx2 = dx * dx;
            float dy = fy - q.z;
            float d2;
            d2 = fmaf(dy, dy, dx2);          g0 = fmaxf(g0, fmaf(-d2, q.w, q.x));
            float dyb = dy + 1.f;
            d2 = fmaf(dyb, dyb, dx2);        g1 = fmaxf(g1, fmaf(-d2, q.w, q.x));
            float dyc = dy + 2.f;
            d2 = fmaf(dyc, dyc, dx2);        g2 = fmaxf(g2, fmaf(-d2, q.w, q.x));
            float dyd = dy + 3.f;
            d2 = fmaf(dyd, dyd, dx2);        g3 = fmaxf(g3, fmaf(-d2, q.w, q.x));
        }
        float v0 = exp2f(g0), v1 = exp2f(g1), v2 = exp2f(g2), v3 = exp2f(g3);
        int base = (b * HH + (blk & 63) * 4) * WW + tid;
        gauss[base]          = v0;
        gauss[base + WW]     = v1;
        gauss[base + 2 * WW] = v2;
        gauss[base + 3 * WW] = v3;

        float tmn = fminf(fminf(v0, v1), fminf(v2, v3));
        float tmx = fmaxf(fmaxf(v0, v1), fmaxf(v2, v3));
        r0[tid] = tmn; r1[tid] = tmx;
        __syncthreads();
        for (int off = 128; off > 0; off >>= 1) {
            if (tid < off) {
                r0[tid] = fminf(r0[tid], r0[tid + off]);
                r1[tid] = fmaxf(r1[tid], r1[tid + off]);
            }
            __syncthreads();
        }
        if (tid == 0) { gmn[blk] = r0[0]; gmx[blk] = r1[0]; }
    }
}

// ============ final norm01 (float4 vectorized) ============
__global__ void k_norm(const float* __restrict__ gauss, const float* __restrict__ gmn,
                       const float* __restrict__ gmx, float* __restrict__ out) {
    int blk = blockIdx.x;
    int b = blk >> 6;
    int tid = threadIdx.x;
    __shared__ float sred[2];
    if (tid < 64) {
        float mn = gmn[b * NTIL + tid];
        float mx = gmx[b * NTIL + tid];
        #pragma unroll
        for (int o = 32; o > 0; o >>= 1) { mn = fminf(mn, __shfl_xor(mn, o, 64)); mx = fmaxf(mx, __shfl_xor(mx, o, 64)); }
        if (tid == 0) { sred[0] = mn; sred[1] = mx; }
    }
    __syncthreads();
    float mn = sred[0];
    float inv = 1.f / (sred[1] - mn + 1e-6f);
    int i = blk * 256 + tid;
    float4 v = ((const float4*)gauss)[i];
    v.x = (v.x - mn) * inv;
    v.y = (v.y - mn) * inv;
    v.z = (v.z - mn) * inv;
    v.w = (v.w - mn) * inv;
    ((float4*)out)[i] = v;
}

extern "C" void kernel_launch(void* const* d_in, const int* in_sizes, int n_in,
                              void* d_out, int out_size, void* d_ws, size_t ws_size,
                              hipStream_t stream) {
    const float* vsm   = (const float*)d_in[0];
    const float* depth = (const float*)d_in[1];
    float* out = (float*)d_out;

    // workspace layout
    float* prod  = (float*)d_ws;                       // TOT
    float* gauss = prod + TOT;                         // TOT
    float* pmn   = gauss + TOT;                        // NBLK
    float* pmx   = pmn + NBLK;
    float* gmn   = pmx + NBLK;
    float* gmx   = gmn + NBLK;
    unsigned* bcnt  = (unsigned*)(gmx + NBLK);         // BB
    unsigned* histg = bcnt + BB;                       // BB*SELBINS
    float* candV = (float*)(histg + BB * SELBINS);     // BB*CAP
    int*   candI = (int*)(candV + BB * CAP);           // BB*CAP

    k_box9  <<<NBLK, 256, 0, stream>>>(vsm, prod, pmn, pmx, histg, bcnt);
    k_nms   <<<NBLK, 256, 0, stream>>>(vsm, prod, pmn, pmx, bcnt, candV, candI, histg);
    k_tsplat<<<NBLK, 256, 0, stream>>>(depth, bcnt, candV, candI, histg, gauss, gmn, gmx);
    k_norm  <<<NBLK, 256, 0, stream>>>(gauss, gmn, gmx, out);
}